// Round 1
// baseline (1657.916 us; speedup 1.0000x reference)
//
#include <hip/hip_runtime.h>
#include <math.h>

#define N_NODES 20000
#define N_EDGES 320000

__device__ __forceinline__ float silu_f(float x) {
    return x / (1.0f + __expf(-x));
}

// ---------------- K1: node pre-GEMMs ----------------
// ys = xs @ w1_s * 1/8 ; sc_s = xs @ wsc_s * 1/8
// yv[n][v][d] = sum_u xv[n][u][d] * w1_v[u][v] * 1/8 ; sc_v similarly
__global__ __launch_bounds__(256) void k1_node_pre(
    const float* __restrict__ nh,
    const float* __restrict__ w1s, const float* __restrict__ w1v,
    const float* __restrict__ wscs, const float* __restrict__ wscv,
    float* __restrict__ ys, float* __restrict__ yv,
    float* __restrict__ scs, float* __restrict__ scv)
{
    __shared__ float lw1s[64*64], lw1v[64*64], lwscs[64*64], lwscv[64*64];
    for (int i = threadIdx.x; i < 64*64; i += 256) {
        lw1s[i] = w1s[i]; lw1v[i] = w1v[i];
        lwscs[i] = wscs[i]; lwscv[i] = wscv[i];
    }
    __syncthreads();
    const int wave = threadIdx.x >> 6, lane = threadIdx.x & 63;
    const int base = blockIdx.x * 32 + wave * 8;
    for (int ni = 0; ni < 8; ++ni) {
        const int n = base + ni;
        if (n >= N_NODES) break;
        const float* row = nh + (size_t)n * 256;
        const float xs  = row[lane];
        const float xv0 = row[64 + lane*3 + 0];
        const float xv1 = row[64 + lane*3 + 1];
        const float xv2 = row[64 + lane*3 + 2];
        float a_ys = 0.f, a_ss = 0.f;
        float a_v0 = 0.f, a_v1 = 0.f, a_v2 = 0.f;
        float a_s0 = 0.f, a_s1 = 0.f, a_s2 = 0.f;
        #pragma unroll 8
        for (int u = 0; u < 64; ++u) {
            const float xsu  = __shfl(xs, u);
            const float x0u  = __shfl(xv0, u);
            const float x1u  = __shfl(xv1, u);
            const float x2u  = __shfl(xv2, u);
            const float w1   = lw1s[u*64 + lane];
            const float wv   = lw1v[u*64 + lane];
            const float wss  = lwscs[u*64 + lane];
            const float wsv  = lwscv[u*64 + lane];
            a_ys += xsu * w1;   a_ss += xsu * wss;
            a_v0 += x0u * wv;   a_v1 += x1u * wv;   a_v2 += x2u * wv;
            a_s0 += x0u * wsv;  a_s1 += x1u * wsv;  a_s2 += x2u * wsv;
        }
        const float inv = 0.125f;  // 1/sqrt(64)
        ys [(size_t)n*64 + lane] = a_ys * inv;
        scs[(size_t)n*64 + lane] = a_ss * inv;
        yv [(size_t)n*192 + lane*3 + 0] = a_v0 * inv;
        yv [(size_t)n*192 + lane*3 + 1] = a_v1 * inv;
        yv [(size_t)n*192 + lane*3 + 2] = a_v2 * inv;
        scv[(size_t)n*192 + lane*3 + 0] = a_s0 * inv;
        scv[(size_t)n*192 + lane*3 + 1] = a_s1 * inv;
        scv[(size_t)n*192 + lane*3 + 2] = a_s2 * inv;
    }
}

// ---------------- K2: per-edge MLP + tensor product + atomic scatter ----------------
__global__ __launch_bounds__(256) void k2_edge(
    const float* __restrict__ edge_attr, const float* __restrict__ edge_sh,
    const int* __restrict__ eidx,
    const float* __restrict__ fcw1, const float* __restrict__ fcw2,
    const float* __restrict__ fcw3,
    const float* __restrict__ ys, const float* __restrict__ yv,
    float* __restrict__ ns, float* __restrict__ nv, float* __restrict__ deg)
{
    __shared__ float lw1[8*64];
    __shared__ float lw2[64*64];
    for (int i = threadIdx.x; i < 8*64; i += 256)  lw1[i] = fcw1[i];
    for (int i = threadIdx.x; i < 64*64; i += 256) lw2[i] = fcw2[i];
    __syncthreads();
    const int lane = threadIdx.x & 63;
    const int e = blockIdx.x * 4 + (threadIdx.x >> 6);
    if (e >= N_EDGES) return;

    // h1 = silu(edge_attr @ fc_w1 / sqrt(8))
    float h1 = 0.f;
    const float* ea = edge_attr + (size_t)e * 8;
    #pragma unroll
    for (int u = 0; u < 8; ++u) h1 += ea[u] * lw1[u*64 + lane];
    h1 = silu_f(h1 * 0.35355339059327373f);

    // h2 = silu(h1 @ fc_w2 / 8)
    float h2 = 0.f;
    #pragma unroll 8
    for (int u = 0; u < 64; ++u) {
        const float h1u = __shfl(h1, u);
        h2 += h1u * lw2[u*64 + lane];
    }
    h2 = silu_f(h2 * 0.125f);

    // w = h2 @ fc_w3 / 8 ; lane v holds wA[v],wB[v],wC[v],wD[v]
    float wa = 0.f, wb = 0.f, wc = 0.f, wd = 0.f;
    #pragma unroll 4
    for (int u = 0; u < 64; ++u) {
        const float h2u = __shfl(h2, u);
        const float* r = fcw3 + u*256;
        wa += h2u * r[lane];
        wb += h2u * r[64  + lane];
        wc += h2u * r[128 + lane];
        wd += h2u * r[192 + lane];
    }
    wa *= 0.125f; wb *= 0.125f; wc *= 0.125f; wd *= 0.125f;

    const int src = eidx[e];
    const int dst = eidx[N_EDGES + e];
    const float sh0  = edge_sh[(size_t)e*4 + 0];
    const float sh1x = edge_sh[(size_t)e*4 + 1];
    const float sh1y = edge_sh[(size_t)e*4 + 2];
    const float sh1z = edge_sh[(size_t)e*4 + 3];

    const float es  = ys[(size_t)dst*64 + lane];
    const float ev0 = yv[(size_t)dst*192 + lane*3 + 0];
    const float ev1 = yv[(size_t)dst*192 + lane*3 + 1];
    const float ev2 = yv[(size_t)dst*192 + lane*3 + 2];

    const float m0a = wa * es * sh0;
    const float dot = ev0*sh1x + ev1*sh1y + ev2*sh1z;
    const float m0b = wd * dot * 0.5773502691896258f;

    float* nsrow = ns + (size_t)src * 128;
    atomicAdd(nsrow + lane,      m0a);
    atomicAdd(nsrow + 64 + lane, m0b);

    float* nvrow = nv + (size_t)src * 384;
    atomicAdd(nvrow + lane*3 + 0, wb * es * sh1x);
    atomicAdd(nvrow + lane*3 + 1, wb * es * sh1y);
    atomicAdd(nvrow + lane*3 + 2, wb * es * sh1z);
    atomicAdd(nvrow + 192 + lane*3 + 0, wc * ev0 * sh0);
    atomicAdd(nvrow + 192 + lane*3 + 1, wc * ev1 * sh0);
    atomicAdd(nvrow + 192 + lane*3 + 2, wc * ev2 * sh0);

    if (lane == 0) atomicAdd(deg + src, 1.0f);
}

// ---------------- K3: node post-GEMM + RMS norm ----------------
__global__ __launch_bounds__(256) void k3_node_post(
    const float* __restrict__ ns, const float* __restrict__ nv,
    const float* __restrict__ deg,
    const float* __restrict__ w2s, const float* __restrict__ w2v,
    const float* __restrict__ scs, const float* __restrict__ scv,
    const float* __restrict__ gs, const float* __restrict__ gv,
    float* __restrict__ out)
{
    __shared__ float lw2s[128*64], lw2v[128*64];
    for (int i = threadIdx.x; i < 128*64; i += 256) {
        lw2s[i] = w2s[i]; lw2v[i] = w2v[i];
    }
    __syncthreads();
    const int wave = threadIdx.x >> 6, lane = threadIdx.x & 63;
    const int base = blockIdx.x * 32 + wave * 8;
    for (int ni = 0; ni < 8; ++ni) {
        const int n = base + ni;
        if (n >= N_NODES) break;
        const float* nsrow = ns + (size_t)n * 128;
        const float* nvrow = nv + (size_t)n * 384;
        const float ns0 = nsrow[lane], ns1 = nsrow[64 + lane];
        const float nva0 = nvrow[lane*3+0], nva1 = nvrow[lane*3+1], nva2 = nvrow[lane*3+2];
        const float nvb0 = nvrow[192+lane*3+0], nvb1 = nvrow[192+lane*3+1], nvb2 = nvrow[192+lane*3+2];
        float aos = 0.f, a0 = 0.f, a1 = 0.f, a2 = 0.f;
        #pragma unroll 8
        for (int u = 0; u < 64; ++u) {
            const float nsu = __shfl(ns0, u);
            const float v0u = __shfl(nva0, u);
            const float v1u = __shfl(nva1, u);
            const float v2u = __shfl(nva2, u);
            const float ws = lw2s[u*64 + lane];
            const float wv = lw2v[u*64 + lane];
            aos += nsu * ws;
            a0 += v0u * wv;  a1 += v1u * wv;  a2 += v2u * wv;
        }
        #pragma unroll 8
        for (int u = 0; u < 64; ++u) {
            const float nsu = __shfl(ns1, u);
            const float v0u = __shfl(nvb0, u);
            const float v1u = __shfl(nvb1, u);
            const float v2u = __shfl(nvb2, u);
            const float ws = lw2s[(64+u)*64 + lane];
            const float wv = lw2v[(64+u)*64 + lane];
            aos += nsu * ws;
            a0 += v0u * wv;  a1 += v1u * wv;  a2 += v2u * wv;
        }
        const float dn = rsqrtf(fmaxf(deg[n], 1.0f));
        const float inv2 = 0.08838834764831845f;  // 1/sqrt(128)
        float os  = aos * inv2 * dn + scs[(size_t)n*64 + lane];
        float ov0 = a0  * inv2 * dn + scv[(size_t)n*192 + lane*3 + 0];
        float ov1 = a1  * inv2 * dn + scv[(size_t)n*192 + lane*3 + 1];
        float ov2 = a2  * inv2 * dn + scv[(size_t)n*192 + lane*3 + 2];

        float ssq = os * os;
        #pragma unroll
        for (int off = 32; off; off >>= 1) ssq += __shfl_xor(ssq, off);
        os *= rsqrtf(ssq * (1.0f/64.0f) + 1e-5f) * gs[lane];

        float vsq = ov0*ov0 + ov1*ov1 + ov2*ov2;
        #pragma unroll
        for (int off = 32; off; off >>= 1) vsq += __shfl_xor(vsq, off);
        const float rv = rsqrtf(vsq * (1.0f/192.0f) + 1e-5f) * gv[lane];
        ov0 *= rv; ov1 *= rv; ov2 *= rv;

        float* orow = out + (size_t)n * 256;
        orow[lane] = os;
        orow[64 + lane*3 + 0] = ov0;
        orow[64 + lane*3 + 1] = ov1;
        orow[64 + lane*3 + 2] = ov2;
    }
}

extern "C" void kernel_launch(void* const* d_in, const int* in_sizes, int n_in,
                              void* d_out, int out_size, void* d_ws, size_t ws_size,
                              hipStream_t stream) {
    const float* nh   = (const float*)d_in[0];
    const float* ea   = (const float*)d_in[1];
    const float* esh  = (const float*)d_in[2];
    const float* w1s  = (const float*)d_in[3];
    const float* w1v  = (const float*)d_in[4];
    const float* wscs = (const float*)d_in[5];
    const float* wscv = (const float*)d_in[6];
    const float* w2s  = (const float*)d_in[7];
    const float* w2v  = (const float*)d_in[8];
    const float* fcw1 = (const float*)d_in[9];
    const float* fcw2 = (const float*)d_in[10];
    const float* fcw3 = (const float*)d_in[11];
    const float* gs   = (const float*)d_in[12];
    const float* gv   = (const float*)d_in[13];
    const int*   eidx = (const int*)d_in[14];
    float* out = (float*)d_out;

    float* ws = (float*)d_ws;
    size_t off = 0;
    float* ys  = ws + off; off += (size_t)N_NODES * 64;
    float* yv  = ws + off; off += (size_t)N_NODES * 192;
    float* scs = ws + off; off += (size_t)N_NODES * 64;
    float* scv = ws + off; off += (size_t)N_NODES * 192;
    float* ns  = ws + off; off += (size_t)N_NODES * 128;
    float* nv  = ws + off; off += (size_t)N_NODES * 384;
    float* deg = ws + off; off += (size_t)N_NODES;

    // zero accumulators (ns, nv, deg are contiguous)
    hipMemsetAsync(ns, 0, (size_t)N_NODES * (128 + 384 + 1) * sizeof(float), stream);

    k1_node_pre<<<(N_NODES + 31)/32, 256, 0, stream>>>(
        nh, w1s, w1v, wscs, wscv, ys, yv, scs, scv);

    k2_edge<<<(N_EDGES + 3)/4, 256, 0, stream>>>(
        ea, esh, eidx, fcw1, fcw2, fcw3, ys, yv, ns, nv, deg);

    k3_node_post<<<(N_NODES + 31)/32, 256, 0, stream>>>(
        ns, nv, deg, w2s, w2v, scs, scv, gs, gv, out);
}

// Round 2
// 618.328 us; speedup vs baseline: 2.6813x; 2.6813x over previous
//
#include <hip/hip_runtime.h>
#include <math.h>

#define N_NODES 20000
#define N_EDGES 320000

__device__ __forceinline__ float silu_f(float x) {
    return x / (1.0f + __expf(-x));
}
// wave-uniform lane broadcast via readlane (VALU/SALU, avoids ds_bpermute)
__device__ __forceinline__ float rlane(float v, int l) {
    return __uint_as_float(__builtin_amdgcn_readlane(__float_as_uint(v), l));
}

// ---------------- sort pass: counting sort of edges by src ----------------
__global__ __launch_bounds__(256) void s_hist(const int* __restrict__ eidx,
                                              int* __restrict__ cnt) {
    const int e = blockIdx.x * 256 + threadIdx.x;
    if (e < N_EDGES) atomicAdd(&cnt[eidx[e]], 1);
}

__global__ __launch_bounds__(1024) void s_scan(const int* __restrict__ cnt,
                                               int* __restrict__ start,
                                               int* __restrict__ cursor) {
    __shared__ int buf[1024];
    __shared__ int carry;
    if (threadIdx.x == 0) carry = 0;
    __syncthreads();
    for (int base = 0; base < N_NODES; base += 1024) {
        const int i = base + threadIdx.x;
        const int v = (i < N_NODES) ? cnt[i] : 0;
        buf[threadIdx.x] = v;
        __syncthreads();
        for (int off = 1; off < 1024; off <<= 1) {
            const int t = (threadIdx.x >= off) ? buf[threadIdx.x - off] : 0;
            __syncthreads();
            buf[threadIdx.x] += t;
            __syncthreads();
        }
        if (i < N_NODES) {
            const int ex = carry + buf[threadIdx.x] - v;  // exclusive
            start[i] = ex;
            cursor[i] = ex;
        }
        __syncthreads();
        if (threadIdx.x == 0) carry += buf[1023];
        __syncthreads();
    }
    if (threadIdx.x == 0) start[N_NODES] = carry;
}

__global__ __launch_bounds__(256) void s_scatter(const int* __restrict__ eidx,
                                                 int* __restrict__ cursor,
                                                 int* __restrict__ perm) {
    const int e = blockIdx.x * 256 + threadIdx.x;
    if (e >= N_EDGES) return;
    const int src = eidx[e];
    const int pos = atomicAdd(&cursor[src], 1);
    perm[pos] = e;
}

// ---------------- K1: node pre-GEMMs ----------------
__global__ __launch_bounds__(256) void k1_node_pre(
    const float* __restrict__ nh,
    const float* __restrict__ w1s, const float* __restrict__ w1v,
    const float* __restrict__ wscs, const float* __restrict__ wscv,
    float* __restrict__ ys, float* __restrict__ yv,
    float* __restrict__ scs, float* __restrict__ scv)
{
    __shared__ float lw1s[64*64], lw1v[64*64], lwscs[64*64], lwscv[64*64];
    for (int i = threadIdx.x; i < 64*64; i += 256) {
        lw1s[i] = w1s[i]; lw1v[i] = w1v[i];
        lwscs[i] = wscs[i]; lwscv[i] = wscv[i];
    }
    __syncthreads();
    const int wave = threadIdx.x >> 6, lane = threadIdx.x & 63;
    const int base = blockIdx.x * 32 + wave * 8;
    for (int ni = 0; ni < 8; ++ni) {
        const int n = base + ni;
        if (n >= N_NODES) break;
        const float* row = nh + (size_t)n * 256;
        const float xs  = row[lane];
        const float xv0 = row[64 + lane*3 + 0];
        const float xv1 = row[64 + lane*3 + 1];
        const float xv2 = row[64 + lane*3 + 2];
        float a_ys = 0.f, a_ss = 0.f;
        float a_v0 = 0.f, a_v1 = 0.f, a_v2 = 0.f;
        float a_s0 = 0.f, a_s1 = 0.f, a_s2 = 0.f;
        #pragma unroll 8
        for (int u = 0; u < 64; ++u) {
            const float xsu  = rlane(xs, u);
            const float x0u  = rlane(xv0, u);
            const float x1u  = rlane(xv1, u);
            const float x2u  = rlane(xv2, u);
            const float w1   = lw1s[u*64 + lane];
            const float wv   = lw1v[u*64 + lane];
            const float wss  = lwscs[u*64 + lane];
            const float wsv  = lwscv[u*64 + lane];
            a_ys += xsu * w1;   a_ss += xsu * wss;
            a_v0 += x0u * wv;   a_v1 += x1u * wv;   a_v2 += x2u * wv;
            a_s0 += x0u * wsv;  a_s1 += x1u * wsv;  a_s2 += x2u * wsv;
        }
        const float inv = 0.125f;  // 1/sqrt(64)
        ys [(size_t)n*64 + lane] = a_ys * inv;
        scs[(size_t)n*64 + lane] = a_ss * inv;
        yv [(size_t)n*192 + lane*3 + 0] = a_v0 * inv;
        yv [(size_t)n*192 + lane*3 + 1] = a_v1 * inv;
        yv [(size_t)n*192 + lane*3 + 2] = a_v2 * inv;
        scv[(size_t)n*192 + lane*3 + 0] = a_s0 * inv;
        scv[(size_t)n*192 + lane*3 + 1] = a_s1 * inv;
        scv[(size_t)n*192 + lane*3 + 2] = a_s2 * inv;
    }
}

// ---------------- K2b: one wave per node, register segment-sum, no atomics ----------------
__global__ __launch_bounds__(256) void k2_seg(
    const float* __restrict__ ea, const float* __restrict__ esh,
    const int* __restrict__ eidx, const int* __restrict__ perm,
    const int* __restrict__ start,
    const float* __restrict__ fcw1, const float* __restrict__ fcw2,
    const float* __restrict__ fcw3,
    const float* __restrict__ ys, const float* __restrict__ yv,
    float* __restrict__ ns, float* __restrict__ nv)
{
    __shared__ float lw1[8*64];
    __shared__ float lw2[64*64];
    for (int i = threadIdx.x; i < 8*64; i += 256)  lw1[i] = fcw1[i];
    for (int i = threadIdx.x; i < 64*64; i += 256) lw2[i] = fcw2[i];
    __syncthreads();
    const int lane = threadIdx.x & 63;
    const int n = blockIdx.x * 4 + (threadIdx.x >> 6);
    if (n >= N_NODES) return;
    const int s0 = start[n], s1 = start[n + 1];

    float acc0 = 0.f, acc1 = 0.f;
    float av0 = 0.f, av1 = 0.f, av2 = 0.f;
    float bv0 = 0.f, bv1 = 0.f, bv2 = 0.f;

    for (int p = s0; p < s1; p += 4) {
        // ---- batch of 4 edges (tail masked: padded edges get w == 0) ----
        int idx[4];
        float h1[4];
        #pragma unroll
        for (int j = 0; j < 4; ++j) {
            const bool ok = (p + j < s1);
            idx[j] = perm[ok ? p + j : p];
            const float* eap = ea + (size_t)idx[j] * 8;
            float a = 0.f;
            #pragma unroll
            for (int u = 0; u < 8; ++u) a += eap[u] * lw1[u*64 + lane];
            a = ok ? a * 0.35355339059327373f : 0.f;  // silu(0)=0 -> w=0 for pad
            h1[j] = silu_f(a);
        }
        float h2[4] = {0.f, 0.f, 0.f, 0.f};
        #pragma unroll 8
        for (int u = 0; u < 64; ++u) {
            const float wv = lw2[u*64 + lane];
            h2[0] += rlane(h1[0], u) * wv;
            h2[1] += rlane(h1[1], u) * wv;
            h2[2] += rlane(h1[2], u) * wv;
            h2[3] += rlane(h1[3], u) * wv;
        }
        #pragma unroll
        for (int j = 0; j < 4; ++j) h2[j] = silu_f(h2[j] * 0.125f) * 0.125f; // fold w-scale

        float wa[4] = {0,0,0,0}, wb[4] = {0,0,0,0}, wc[4] = {0,0,0,0}, wd[4] = {0,0,0,0};
        #pragma unroll 4
        for (int u = 0; u < 64; ++u) {
            const float* r = fcw3 + u * 256;
            const float r0 = r[lane], r1 = r[64 + lane], r2 = r[128 + lane], r3 = r[192 + lane];
            #pragma unroll
            for (int j = 0; j < 4; ++j) {
                const float hu = rlane(h2[j], u);
                wa[j] += hu * r0; wb[j] += hu * r1; wc[j] += hu * r2; wd[j] += hu * r3;
            }
        }
        #pragma unroll
        for (int j = 0; j < 4; ++j) {
            const int e = idx[j];
            const int dst = eidx[N_EDGES + e];
            const float sh0  = esh[(size_t)e*4 + 0];
            const float sh1x = esh[(size_t)e*4 + 1];
            const float sh1y = esh[(size_t)e*4 + 2];
            const float sh1z = esh[(size_t)e*4 + 3];
            const float es  = ys[(size_t)dst*64 + lane];
            const float ev0 = yv[(size_t)dst*192 + lane*3 + 0];
            const float ev1 = yv[(size_t)dst*192 + lane*3 + 1];
            const float ev2 = yv[(size_t)dst*192 + lane*3 + 2];
            acc0 += wa[j] * es * sh0;
            acc1 += wd[j] * (ev0*sh1x + ev1*sh1y + ev2*sh1z) * 0.5773502691896258f;
            av0 += wb[j] * es * sh1x;
            av1 += wb[j] * es * sh1y;
            av2 += wb[j] * es * sh1z;
            bv0 += wc[j] * ev0 * sh0;
            bv1 += wc[j] * ev1 * sh0;
            bv2 += wc[j] * ev2 * sh0;
        }
    }
    float* nsrow = ns + (size_t)n * 128;
    nsrow[lane]      = acc0;
    nsrow[64 + lane] = acc1;
    float* nvrow = nv + (size_t)n * 384;
    nvrow[lane*3 + 0] = av0; nvrow[lane*3 + 1] = av1; nvrow[lane*3 + 2] = av2;
    nvrow[192 + lane*3 + 0] = bv0; nvrow[192 + lane*3 + 1] = bv1; nvrow[192 + lane*3 + 2] = bv2;
}

// ---------------- K3: node post-GEMM + RMS norm ----------------
__global__ __launch_bounds__(256) void k3_node_post(
    const float* __restrict__ ns, const float* __restrict__ nv,
    const int* __restrict__ start,
    const float* __restrict__ w2s, const float* __restrict__ w2v,
    const float* __restrict__ scs, const float* __restrict__ scv,
    const float* __restrict__ gs, const float* __restrict__ gv,
    float* __restrict__ out)
{
    __shared__ float lw2s[128*64], lw2v[128*64];
    for (int i = threadIdx.x; i < 128*64; i += 256) {
        lw2s[i] = w2s[i]; lw2v[i] = w2v[i];
    }
    __syncthreads();
    const int wave = threadIdx.x >> 6, lane = threadIdx.x & 63;
    const int base = blockIdx.x * 32 + wave * 8;
    for (int ni = 0; ni < 8; ++ni) {
        const int n = base + ni;
        if (n >= N_NODES) break;
        const float* nsrow = ns + (size_t)n * 128;
        const float* nvrow = nv + (size_t)n * 384;
        const float ns0 = nsrow[lane], ns1 = nsrow[64 + lane];
        const float nva0 = nvrow[lane*3+0], nva1 = nvrow[lane*3+1], nva2 = nvrow[lane*3+2];
        const float nvb0 = nvrow[192+lane*3+0], nvb1 = nvrow[192+lane*3+1], nvb2 = nvrow[192+lane*3+2];
        float aos = 0.f, a0 = 0.f, a1 = 0.f, a2 = 0.f;
        #pragma unroll 8
        for (int u = 0; u < 64; ++u) {
            const float nsu = rlane(ns0, u);
            const float v0u = rlane(nva0, u);
            const float v1u = rlane(nva1, u);
            const float v2u = rlane(nva2, u);
            const float ws = lw2s[u*64 + lane];
            const float wv = lw2v[u*64 + lane];
            aos += nsu * ws;
            a0 += v0u * wv;  a1 += v1u * wv;  a2 += v2u * wv;
        }
        #pragma unroll 8
        for (int u = 0; u < 64; ++u) {
            const float nsu = rlane(ns1, u);
            const float v0u = rlane(nvb0, u);
            const float v1u = rlane(nvb1, u);
            const float v2u = rlane(nvb2, u);
            const float ws = lw2s[(64+u)*64 + lane];
            const float wv = lw2v[(64+u)*64 + lane];
            aos += nsu * ws;
            a0 += v0u * wv;  a1 += v1u * wv;  a2 += v2u * wv;
        }
        const float degf = (float)(start[n+1] - start[n]);
        const float dn = rsqrtf(fmaxf(degf, 1.0f));
        const float inv2 = 0.08838834764831845f;  // 1/sqrt(128)
        float os  = aos * inv2 * dn + scs[(size_t)n*64 + lane];
        float ov0 = a0  * inv2 * dn + scv[(size_t)n*192 + lane*3 + 0];
        float ov1 = a1  * inv2 * dn + scv[(size_t)n*192 + lane*3 + 1];
        float ov2 = a2  * inv2 * dn + scv[(size_t)n*192 + lane*3 + 2];

        float ssq = os * os;
        #pragma unroll
        for (int off = 32; off; off >>= 1) ssq += __shfl_xor(ssq, off);
        os *= rsqrtf(ssq * (1.0f/64.0f) + 1e-5f) * gs[lane];

        float vsq = ov0*ov0 + ov1*ov1 + ov2*ov2;
        #pragma unroll
        for (int off = 32; off; off >>= 1) vsq += __shfl_xor(vsq, off);
        const float rv = rsqrtf(vsq * (1.0f/192.0f) + 1e-5f) * gv[lane];
        ov0 *= rv; ov1 *= rv; ov2 *= rv;

        float* orow = out + (size_t)n * 256;
        orow[lane] = os;
        orow[64 + lane*3 + 0] = ov0;
        orow[64 + lane*3 + 1] = ov1;
        orow[64 + lane*3 + 2] = ov2;
    }
}

extern "C" void kernel_launch(void* const* d_in, const int* in_sizes, int n_in,
                              void* d_out, int out_size, void* d_ws, size_t ws_size,
                              hipStream_t stream) {
    const float* nh   = (const float*)d_in[0];
    const float* ea   = (const float*)d_in[1];
    const float* esh  = (const float*)d_in[2];
    const float* w1s  = (const float*)d_in[3];
    const float* w1v  = (const float*)d_in[4];
    const float* wscs = (const float*)d_in[5];
    const float* wscv = (const float*)d_in[6];
    const float* w2s  = (const float*)d_in[7];
    const float* w2v  = (const float*)d_in[8];
    const float* fcw1 = (const float*)d_in[9];
    const float* fcw2 = (const float*)d_in[10];
    const float* fcw3 = (const float*)d_in[11];
    const float* gs   = (const float*)d_in[12];
    const float* gv   = (const float*)d_in[13];
    const int*   eidx = (const int*)d_in[14];
    float* out = (float*)d_out;

    float* wsf = (float*)d_ws;
    size_t off = 0;
    float* ys  = wsf + off; off += (size_t)N_NODES * 64;
    float* yv  = wsf + off; off += (size_t)N_NODES * 192;
    float* scs = wsf + off; off += (size_t)N_NODES * 64;
    float* scv = wsf + off; off += (size_t)N_NODES * 192;
    float* ns  = wsf + off; off += (size_t)N_NODES * 128;
    float* nv  = wsf + off; off += (size_t)N_NODES * 384;
    int* ibase  = (int*)(wsf + off);
    int* cnt    = ibase;
    int* start  = ibase + N_NODES;            // N_NODES+1
    int* cursor = ibase + 2*N_NODES + 1;
    int* perm   = ibase + 3*N_NODES + 1;      // N_EDGES

    // zero histogram bins only (80 KB)
    hipMemsetAsync(cnt, 0, N_NODES * sizeof(int), stream);

    s_hist<<<(N_EDGES + 255)/256, 256, 0, stream>>>(eidx, cnt);
    s_scan<<<1, 1024, 0, stream>>>(cnt, start, cursor);
    s_scatter<<<(N_EDGES + 255)/256, 256, 0, stream>>>(eidx, cursor, perm);

    k1_node_pre<<<(N_NODES + 31)/32, 256, 0, stream>>>(
        nh, w1s, w1v, wscs, wscv, ys, yv, scs, scv);

    k2_seg<<<(N_NODES + 3)/4, 256, 0, stream>>>(
        ea, esh, eidx, perm, start, fcw1, fcw2, fcw3, ys, yv, ns, nv);

    k3_node_post<<<(N_NODES + 31)/32, 256, 0, stream>>>(
        ns, nv, start, w2s, w2v, scs, scv, gs, gv, out);
}

// Round 3
// 502.399 us; speedup vs baseline: 3.3000x; 1.2307x over previous
//
#include <hip/hip_runtime.h>
#include <math.h>

#define N_NODES 20000
#define N_EDGES 320000

typedef __attribute__((ext_vector_type(8))) short bf16x8;
typedef __attribute__((ext_vector_type(4))) short s16x4;
typedef __attribute__((ext_vector_type(4))) float f32x4;

__device__ __forceinline__ float silu_f(float x) {
    return x / (1.0f + __expf(-x));
}
__device__ __forceinline__ short f2bf(float x) {
    union { float f; unsigned u; } v; v.f = x;
    unsigned r = (v.u + 0x7FFFu + ((v.u >> 16) & 1u)) >> 16;
    return (short)r;
}
__device__ __forceinline__ float bf2f(short h) {
    union { unsigned u; float f; } v; v.u = ((unsigned)(unsigned short)h) << 16;
    return v.f;
}
__device__ __forceinline__ float rlane(float v, int l) {
    return __uint_as_float(__builtin_amdgcn_readlane(__float_as_uint(v), l));
}

// ---------------- sort pass: counting sort of edges by src ----------------
__global__ __launch_bounds__(256) void s_hist(const int* __restrict__ eidx,
                                              int* __restrict__ cnt) {
    const int e = blockIdx.x * 256 + threadIdx.x;
    if (e < N_EDGES) atomicAdd(&cnt[eidx[e]], 1);
}

__global__ __launch_bounds__(1024) void s_scan(const int* __restrict__ cnt,
                                               int* __restrict__ start,
                                               int* __restrict__ cursor) {
    __shared__ int buf[1024];
    __shared__ int carry;
    if (threadIdx.x == 0) carry = 0;
    __syncthreads();
    for (int base = 0; base < N_NODES; base += 1024) {
        const int i = base + threadIdx.x;
        const int v = (i < N_NODES) ? cnt[i] : 0;
        buf[threadIdx.x] = v;
        __syncthreads();
        for (int off = 1; off < 1024; off <<= 1) {
            const int t = (threadIdx.x >= off) ? buf[threadIdx.x - off] : 0;
            __syncthreads();
            buf[threadIdx.x] += t;
            __syncthreads();
        }
        if (i < N_NODES) {
            const int ex = carry + buf[threadIdx.x] - v;  // exclusive
            start[i] = ex;
            cursor[i] = ex;
        }
        __syncthreads();
        if (threadIdx.x == 0) carry += buf[1023];
        __syncthreads();
    }
    if (threadIdx.x == 0) start[N_NODES] = carry;
}

__global__ __launch_bounds__(256) void s_scatter(const int* __restrict__ eidx,
                                                 int* __restrict__ cursor,
                                                 int* __restrict__ perm) {
    const int e = blockIdx.x * 256 + threadIdx.x;
    if (e >= N_EDGES) return;
    const int src = eidx[e];
    const int pos = atomicAdd(&cursor[src], 1);
    perm[pos] = e;
}

// ---------------- K1: node pre-GEMMs ----------------
__global__ __launch_bounds__(256) void k1_node_pre(
    const float* __restrict__ nh,
    const float* __restrict__ w1s, const float* __restrict__ w1v,
    const float* __restrict__ wscs, const float* __restrict__ wscv,
    float* __restrict__ ys, float* __restrict__ yv,
    float* __restrict__ scs, float* __restrict__ scv)
{
    __shared__ float lw1s[64*64], lw1v[64*64], lwscs[64*64], lwscv[64*64];
    for (int i = threadIdx.x; i < 64*64; i += 256) {
        lw1s[i] = w1s[i]; lw1v[i] = w1v[i];
        lwscs[i] = wscs[i]; lwscv[i] = wscv[i];
    }
    __syncthreads();
    const int wave = threadIdx.x >> 6, lane = threadIdx.x & 63;
    const int base = blockIdx.x * 32 + wave * 8;
    for (int ni = 0; ni < 8; ++ni) {
        const int n = base + ni;
        if (n >= N_NODES) break;
        const float* row = nh + (size_t)n * 256;
        const float xs  = row[lane];
        const float xv0 = row[64 + lane*3 + 0];
        const float xv1 = row[64 + lane*3 + 1];
        const float xv2 = row[64 + lane*3 + 2];
        float a_ys = 0.f, a_ss = 0.f;
        float a_v0 = 0.f, a_v1 = 0.f, a_v2 = 0.f;
        float a_s0 = 0.f, a_s1 = 0.f, a_s2 = 0.f;
        #pragma unroll 8
        for (int u = 0; u < 64; ++u) {
            const float xsu  = rlane(xs, u);
            const float x0u  = rlane(xv0, u);
            const float x1u  = rlane(xv1, u);
            const float x2u  = rlane(xv2, u);
            const float w1   = lw1s[u*64 + lane];
            const float wv   = lw1v[u*64 + lane];
            const float wss  = lwscs[u*64 + lane];
            const float wsv  = lwscv[u*64 + lane];
            a_ys += xsu * w1;   a_ss += xsu * wss;
            a_v0 += x0u * wv;   a_v1 += x1u * wv;   a_v2 += x2u * wv;
            a_s0 += x0u * wsv;  a_s1 += x1u * wsv;  a_s2 += x2u * wsv;
        }
        const float inv = 0.125f;
        ys [(size_t)n*64 + lane] = a_ys * inv;
        scs[(size_t)n*64 + lane] = a_ss * inv;
        yv [(size_t)n*192 + lane*3 + 0] = a_v0 * inv;
        yv [(size_t)n*192 + lane*3 + 1] = a_v1 * inv;
        yv [(size_t)n*192 + lane*3 + 2] = a_v2 * inv;
        scv[(size_t)n*192 + lane*3 + 0] = a_s0 * inv;
        scv[(size_t)n*192 + lane*3 + 1] = a_s1 * inv;
        scv[(size_t)n*192 + lane*3 + 2] = a_s2 * inv;
    }
}

// ---------------- K_mlp: MFMA bf16 edge-MLP, 64 edges/wave ----------------
// Weights transposed ([out_ch][k]) in LDS, rows 128B, k XOR-swizzled by
// (ch&7)<<3 (ushort units) -> bank-conflict-free b128 fragment reads.
// Output: wq[slot][ch][4] bf16 = {wA,wB,wC,wD}, slot = perm order.
__global__ __launch_bounds__(256) void k_mlp(
    const float* __restrict__ ea, const int* __restrict__ perm,
    const float* __restrict__ fcw1, const float* __restrict__ fcw2,
    const float* __restrict__ fcw3, short* __restrict__ wq)
{
    __shared__ short lw1t[64*64];   // [v][k0..63], k>=8 zero
    __shared__ short lw2t[64*64];   // [v][u]
    __shared__ short lw3t[256*64];  // [c][u]
    __shared__ short hbA[4][16*64]; // per-wave h1 [row][ch]
    __shared__ short hbB[4][16*64]; // per-wave h2

    for (int i = threadIdx.x; i < 64*64; i += 256) lw1t[i] = 0;
    __syncthreads();
    for (int i = threadIdx.x; i < 8*64; i += 256) {
        const int u = i >> 6, v = i & 63;
        lw1t[v*64 + (u ^ ((v & 7) << 3))] = f2bf(fcw1[i]);
    }
    for (int i = threadIdx.x; i < 64*64; i += 256) {
        const int u = i >> 6, v = i & 63;
        lw2t[v*64 + (u ^ ((v & 7) << 3))] = f2bf(fcw2[i]);
    }
    for (int i = threadIdx.x; i < 256*64; i += 256) {
        const int u = i >> 8, c = i & 255;
        lw3t[c*64 + (u ^ ((c & 7) << 3))] = f2bf(fcw3[(size_t)u*256 + c]);
    }
    __syncthreads();

    const int lane = threadIdx.x & 63;
    const int w = threadIdx.x >> 6;
    const int l15 = lane & 15, lhi = lane >> 4;
    const int swz = (l15 & 7) << 3;           // == (col&7)<<3 for col=nb*16+l15
    const int wbase = (blockIdx.x * 4 + w) * 64;
    const f32x4 zz = {0.f, 0.f, 0.f, 0.f};

    // hoist B fragments for L1/L2
    bf16x8 b1[4], b2[4][2];
    #pragma unroll
    for (int nb = 0; nb < 4; ++nb) {
        const int col = nb*16 + l15;
        b1[nb] = *(const bf16x8*)&lw1t[col*64 + ((lhi*8) ^ swz)];
        #pragma unroll
        for (int kk = 0; kk < 2; ++kk)
            b2[nb][kk] = *(const bf16x8*)&lw2t[col*64 + ((kk*32 + lhi*8) ^ swz)];
    }

    bf16x8 a3[4][2];
    for (int sb = 0; sb < 4; ++sb) {
        // ---- L1: A = edge_attr rows (K=8, padded to 32 with zeros) ----
        bf16x8 a1 = {0,0,0,0,0,0,0,0};
        if (lhi == 0) {
            const int e = perm[wbase + sb*16 + l15];
            const float4 p0 = *(const float4*)(ea + (size_t)e*8);
            const float4 p1 = *(const float4*)(ea + (size_t)e*8 + 4);
            a1[0]=f2bf(p0.x); a1[1]=f2bf(p0.y); a1[2]=f2bf(p0.z); a1[3]=f2bf(p0.w);
            a1[4]=f2bf(p1.x); a1[5]=f2bf(p1.y); a1[6]=f2bf(p1.z); a1[7]=f2bf(p1.w);
        }
        f32x4 d1[4];
        #pragma unroll
        for (int nb = 0; nb < 4; ++nb)
            d1[nb] = __builtin_amdgcn_mfma_f32_16x16x32_bf16(a1, b1[nb], zz, 0,0,0);
        #pragma unroll
        for (int nb = 0; nb < 4; ++nb)
            #pragma unroll
            for (int r = 0; r < 4; ++r) {
                const int row = lhi*4 + r, ch = nb*16 + l15;
                hbA[w][row*64 + (ch ^ ((row & 7) << 3))] =
                    f2bf(silu_f(d1[nb][r] * 0.35355339059327373f));
            }
        // ---- L2 ----
        bf16x8 a2[2];
        #pragma unroll
        for (int kk = 0; kk < 2; ++kk)
            a2[kk] = *(const bf16x8*)&hbA[w][l15*64 + ((kk*32 + lhi*8) ^ swz)];
        f32x4 d2[4];
        #pragma unroll
        for (int nb = 0; nb < 4; ++nb) {
            d2[nb] = __builtin_amdgcn_mfma_f32_16x16x32_bf16(a2[0], b2[nb][0], zz, 0,0,0);
            d2[nb] = __builtin_amdgcn_mfma_f32_16x16x32_bf16(a2[1], b2[nb][1], d2[nb], 0,0,0);
        }
        #pragma unroll
        for (int nb = 0; nb < 4; ++nb)
            #pragma unroll
            for (int r = 0; r < 4; ++r) {
                const int row = lhi*4 + r, ch = nb*16 + l15;
                hbB[w][row*64 + (ch ^ ((row & 7) << 3))] =
                    f2bf(silu_f(d2[nb][r] * 0.125f) * 0.125f);  // fold final 1/8
            }
        #pragma unroll
        for (int kk = 0; kk < 2; ++kk)
            a3[sb][kk] = *(const bf16x8*)&hbB[w][l15*64 + ((kk*32 + lhi*8) ^ swz)];
    }

    // ---- L3: N=256, packed {wA,wB,wC,wD} stores ----
    #pragma unroll
    for (int ch4 = 0; ch4 < 4; ++ch4) {
        f32x4 dq[4][4];  // [sb][q]
        #pragma unroll
        for (int q = 0; q < 4; ++q) {
            const int col = (q*4 + ch4)*16 + l15;
            const bf16x8 b30 = *(const bf16x8*)&lw3t[col*64 + ((lhi*8) ^ swz)];
            const bf16x8 b31 = *(const bf16x8*)&lw3t[col*64 + ((32 + lhi*8) ^ swz)];
            #pragma unroll
            for (int sb = 0; sb < 4; ++sb) {
                f32x4 t = __builtin_amdgcn_mfma_f32_16x16x32_bf16(a3[sb][0], b30, zz, 0,0,0);
                dq[sb][q] = __builtin_amdgcn_mfma_f32_16x16x32_bf16(a3[sb][1], b31, t, 0,0,0);
            }
        }
        #pragma unroll
        for (int sb = 0; sb < 4; ++sb)
            #pragma unroll
            for (int r = 0; r < 4; ++r) {
                const int slot = wbase + sb*16 + lhi*4 + r;
                s16x4 v;
                v[0] = f2bf(dq[sb][0][r]);
                v[1] = f2bf(dq[sb][1][r]);
                v[2] = f2bf(dq[sb][2][r]);
                v[3] = f2bf(dq[sb][3][r]);
                *(s16x4*)&wq[((size_t)slot*64 + ch4*16 + l15) * 4] = v;
            }
    }
}

// ---------------- K2: per-node gather + register segment-sum ----------------
__global__ __launch_bounds__(256) void k2_gather(
    const float* __restrict__ esh, const int* __restrict__ eidx,
    const int* __restrict__ perm, const int* __restrict__ start,
    const short* __restrict__ wq,
    const float* __restrict__ ys, const float* __restrict__ yv,
    float* __restrict__ ns, float* __restrict__ nv)
{
    const int lane = threadIdx.x & 63;
    const int n = blockIdx.x * 4 + (threadIdx.x >> 6);
    if (n >= N_NODES) return;
    const int s0 = start[n], s1 = start[n + 1];
    float acc0=0.f, acc1=0.f, av0=0.f, av1=0.f, av2=0.f, bv0=0.f, bv1=0.f, bv2=0.f;
    for (int p = s0; p < s1; ++p) {
        const int e = perm[p];
        const int dst = eidx[N_EDGES + e];
        const float4 sh = *(const float4*)(esh + (size_t)e*4);
        const s16x4 wv = *(const s16x4*)&wq[((size_t)p*64 + lane) * 4];
        const float wa = bf2f(wv[0]), wb = bf2f(wv[1]);
        const float wc = bf2f(wv[2]), wd = bf2f(wv[3]);
        const float es  = ys[(size_t)dst*64 + lane];
        const float ev0 = yv[(size_t)dst*192 + lane*3 + 0];
        const float ev1 = yv[(size_t)dst*192 + lane*3 + 1];
        const float ev2 = yv[(size_t)dst*192 + lane*3 + 2];
        acc0 += wa * es * sh.x;
        acc1 += wd * (ev0*sh.y + ev1*sh.z + ev2*sh.w) * 0.5773502691896258f;
        const float esb = wb * es;
        av0 += esb * sh.y; av1 += esb * sh.z; av2 += esb * sh.w;
        const float c0 = wc * sh.x;
        bv0 += c0 * ev0; bv1 += c0 * ev1; bv2 += c0 * ev2;
    }
    float* nsrow = ns + (size_t)n * 128;
    nsrow[lane]      = acc0;
    nsrow[64 + lane] = acc1;
    float* nvrow = nv + (size_t)n * 384;
    nvrow[lane*3 + 0] = av0; nvrow[lane*3 + 1] = av1; nvrow[lane*3 + 2] = av2;
    nvrow[192 + lane*3 + 0] = bv0; nvrow[192 + lane*3 + 1] = bv1; nvrow[192 + lane*3 + 2] = bv2;
}

// ---------------- fallback K2 (round-2, used if ws too small) ----------------
__global__ __launch_bounds__(256) void k2_seg(
    const float* __restrict__ ea, const float* __restrict__ esh,
    const int* __restrict__ eidx, const int* __restrict__ perm,
    const int* __restrict__ start,
    const float* __restrict__ fcw1, const float* __restrict__ fcw2,
    const float* __restrict__ fcw3,
    const float* __restrict__ ys, const float* __restrict__ yv,
    float* __restrict__ ns, float* __restrict__ nv)
{
    __shared__ float lw1[8*64];
    __shared__ float lw2[64*64];
    for (int i = threadIdx.x; i < 8*64; i += 256)  lw1[i] = fcw1[i];
    for (int i = threadIdx.x; i < 64*64; i += 256) lw2[i] = fcw2[i];
    __syncthreads();
    const int lane = threadIdx.x & 63;
    const int n = blockIdx.x * 4 + (threadIdx.x >> 6);
    if (n >= N_NODES) return;
    const int s0 = start[n], s1 = start[n + 1];
    float acc0 = 0.f, acc1 = 0.f;
    float av0 = 0.f, av1 = 0.f, av2 = 0.f;
    float bv0 = 0.f, bv1 = 0.f, bv2 = 0.f;
    for (int p = s0; p < s1; p += 4) {
        int idx[4];
        float h1[4];
        #pragma unroll
        for (int j = 0; j < 4; ++j) {
            const bool ok = (p + j < s1);
            idx[j] = perm[ok ? p + j : p];
            const float* eap = ea + (size_t)idx[j] * 8;
            float a = 0.f;
            #pragma unroll
            for (int u = 0; u < 8; ++u) a += eap[u] * lw1[u*64 + lane];
            a = ok ? a * 0.35355339059327373f : 0.f;
            h1[j] = silu_f(a);
        }
        float h2[4] = {0.f, 0.f, 0.f, 0.f};
        #pragma unroll 8
        for (int u = 0; u < 64; ++u) {
            const float wv = lw2[u*64 + lane];
            h2[0] += rlane(h1[0], u) * wv;
            h2[1] += rlane(h1[1], u) * wv;
            h2[2] += rlane(h1[2], u) * wv;
            h2[3] += rlane(h1[3], u) * wv;
        }
        #pragma unroll
        for (int j = 0; j < 4; ++j) h2[j] = silu_f(h2[j] * 0.125f) * 0.125f;
        float wa[4] = {0,0,0,0}, wb[4] = {0,0,0,0}, wc[4] = {0,0,0,0}, wd[4] = {0,0,0,0};
        #pragma unroll 4
        for (int u = 0; u < 64; ++u) {
            const float* r = fcw3 + u * 256;
            const float r0 = r[lane], r1 = r[64 + lane], r2 = r[128 + lane], r3 = r[192 + lane];
            #pragma unroll
            for (int j = 0; j < 4; ++j) {
                const float hu = rlane(h2[j], u);
                wa[j] += hu * r0; wb[j] += hu * r1; wc[j] += hu * r2; wd[j] += hu * r3;
            }
        }
        #pragma unroll
        for (int j = 0; j < 4; ++j) {
            const int e = idx[j];
            const int dst = eidx[N_EDGES + e];
            const float sh0  = esh[(size_t)e*4 + 0];
            const float sh1x = esh[(size_t)e*4 + 1];
            const float sh1y = esh[(size_t)e*4 + 2];
            const float sh1z = esh[(size_t)e*4 + 3];
            const float es  = ys[(size_t)dst*64 + lane];
            const float ev0 = yv[(size_t)dst*192 + lane*3 + 0];
            const float ev1 = yv[(size_t)dst*192 + lane*3 + 1];
            const float ev2 = yv[(size_t)dst*192 + lane*3 + 2];
            acc0 += wa[j] * es * sh0;
            acc1 += wd[j] * (ev0*sh1x + ev1*sh1y + ev2*sh1z) * 0.5773502691896258f;
            av0 += wb[j] * es * sh1x;
            av1 += wb[j] * es * sh1y;
            av2 += wb[j] * es * sh1z;
            bv0 += wc[j] * ev0 * sh0;
            bv1 += wc[j] * ev1 * sh0;
            bv2 += wc[j] * ev2 * sh0;
        }
    }
    float* nsrow = ns + (size_t)n * 128;
    nsrow[lane]      = acc0;
    nsrow[64 + lane] = acc1;
    float* nvrow = nv + (size_t)n * 384;
    nvrow[lane*3 + 0] = av0; nvrow[lane*3 + 1] = av1; nvrow[lane*3 + 2] = av2;
    nvrow[192 + lane*3 + 0] = bv0; nvrow[192 + lane*3 + 1] = bv1; nvrow[192 + lane*3 + 2] = bv2;
}

// ---------------- K3: node post-GEMM + RMS norm ----------------
__global__ __launch_bounds__(256) void k3_node_post(
    const float* __restrict__ ns, const float* __restrict__ nv,
    const int* __restrict__ start,
    const float* __restrict__ w2s, const float* __restrict__ w2v,
    const float* __restrict__ scs, const float* __restrict__ scv,
    const float* __restrict__ gs, const float* __restrict__ gv,
    float* __restrict__ out)
{
    __shared__ float lw2s[128*64], lw2v[128*64];
    for (int i = threadIdx.x; i < 128*64; i += 256) {
        lw2s[i] = w2s[i]; lw2v[i] = w2v[i];
    }
    __syncthreads();
    const int wave = threadIdx.x >> 6, lane = threadIdx.x & 63;
    const int base = blockIdx.x * 32 + wave * 8;
    for (int ni = 0; ni < 8; ++ni) {
        const int n = base + ni;
        if (n >= N_NODES) break;
        const float* nsrow = ns + (size_t)n * 128;
        const float* nvrow = nv + (size_t)n * 384;
        const float ns0 = nsrow[lane], ns1 = nsrow[64 + lane];
        const float nva0 = nvrow[lane*3+0], nva1 = nvrow[lane*3+1], nva2 = nvrow[lane*3+2];
        const float nvb0 = nvrow[192+lane*3+0], nvb1 = nvrow[192+lane*3+1], nvb2 = nvrow[192+lane*3+2];
        float aos = 0.f, a0 = 0.f, a1 = 0.f, a2 = 0.f;
        #pragma unroll 8
        for (int u = 0; u < 64; ++u) {
            const float nsu = rlane(ns0, u);
            const float v0u = rlane(nva0, u);
            const float v1u = rlane(nva1, u);
            const float v2u = rlane(nva2, u);
            const float ws = lw2s[u*64 + lane];
            const float wv = lw2v[u*64 + lane];
            aos += nsu * ws;
            a0 += v0u * wv;  a1 += v1u * wv;  a2 += v2u * wv;
        }
        #pragma unroll 8
        for (int u = 0; u < 64; ++u) {
            const float nsu = rlane(ns1, u);
            const float v0u = rlane(nvb0, u);
            const float v1u = rlane(nvb1, u);
            const float v2u = rlane(nvb2, u);
            const float ws = lw2s[(64+u)*64 + lane];
            const float wv = lw2v[(64+u)*64 + lane];
            aos += nsu * ws;
            a0 += v0u * wv;  a1 += v1u * wv;  a2 += v2u * wv;
        }
        const float degf = (float)(start[n+1] - start[n]);
        const float dn = rsqrtf(fmaxf(degf, 1.0f));
        const float inv2 = 0.08838834764831845f;
        float os  = aos * inv2 * dn + scs[(size_t)n*64 + lane];
        float ov0 = a0  * inv2 * dn + scv[(size_t)n*192 + lane*3 + 0];
        float ov1 = a1  * inv2 * dn + scv[(size_t)n*192 + lane*3 + 1];
        float ov2 = a2  * inv2 * dn + scv[(size_t)n*192 + lane*3 + 2];

        float ssq = os * os;
        #pragma unroll
        for (int off = 32; off; off >>= 1) ssq += __shfl_xor(ssq, off);
        os *= rsqrtf(ssq * (1.0f/64.0f) + 1e-5f) * gs[lane];

        float vsq = ov0*ov0 + ov1*ov1 + ov2*ov2;
        #pragma unroll
        for (int off = 32; off; off >>= 1) vsq += __shfl_xor(vsq, off);
        const float rv = rsqrtf(vsq * (1.0f/192.0f) + 1e-5f) * gv[lane];
        ov0 *= rv; ov1 *= rv; ov2 *= rv;

        float* orow = out + (size_t)n * 256;
        orow[lane] = os;
        orow[64 + lane*3 + 0] = ov0;
        orow[64 + lane*3 + 1] = ov1;
        orow[64 + lane*3 + 2] = ov2;
    }
}

extern "C" void kernel_launch(void* const* d_in, const int* in_sizes, int n_in,
                              void* d_out, int out_size, void* d_ws, size_t ws_size,
                              hipStream_t stream) {
    const float* nh   = (const float*)d_in[0];
    const float* ea   = (const float*)d_in[1];
    const float* esh  = (const float*)d_in[2];
    const float* w1s  = (const float*)d_in[3];
    const float* w1v  = (const float*)d_in[4];
    const float* wscs = (const float*)d_in[5];
    const float* wscv = (const float*)d_in[6];
    const float* w2s  = (const float*)d_in[7];
    const float* w2v  = (const float*)d_in[8];
    const float* fcw1 = (const float*)d_in[9];
    const float* fcw2 = (const float*)d_in[10];
    const float* fcw3 = (const float*)d_in[11];
    const float* gs   = (const float*)d_in[12];
    const float* gv   = (const float*)d_in[13];
    const int*   eidx = (const int*)d_in[14];
    float* out = (float*)d_out;

    float* wsf = (float*)d_ws;
    size_t off = 0;
    float* ys  = wsf + off; off += (size_t)N_NODES * 64;
    float* yv  = wsf + off; off += (size_t)N_NODES * 192;
    float* scs = wsf + off; off += (size_t)N_NODES * 64;
    float* scv = wsf + off; off += (size_t)N_NODES * 192;
    float* ns  = wsf + off; off += (size_t)N_NODES * 128;
    float* nv  = wsf + off; off += (size_t)N_NODES * 384;
    int* ibase  = (int*)(wsf + off);
    int* cnt    = ibase;
    int* start  = ibase + N_NODES;            // N_NODES+1
    int* cursor = ibase + 2*N_NODES + 1;
    int* perm   = ibase + 3*N_NODES + 1;      // N_EDGES
    // wq after ints, 16B aligned
    size_t ibytes = ((size_t)wsf + off*4 - (size_t)d_ws) + (3*(size_t)N_NODES + 1 + N_EDGES)*4;
    size_t wq_off = (ibytes + 15) & ~(size_t)15;
    short* wq = (short*)((char*)d_ws + wq_off);
    const size_t need = wq_off + (size_t)N_EDGES * 64 * 4 * 2;

    hipMemsetAsync(cnt, 0, N_NODES * sizeof(int), stream);

    s_hist<<<(N_EDGES + 255)/256, 256, 0, stream>>>(eidx, cnt);
    s_scan<<<1, 1024, 0, stream>>>(cnt, start, cursor);
    s_scatter<<<(N_EDGES + 255)/256, 256, 0, stream>>>(eidx, cursor, perm);

    k1_node_pre<<<(N_NODES + 31)/32, 256, 0, stream>>>(
        nh, w1s, w1v, wscs, wscv, ys, yv, scs, scv);

    if (ws_size >= need) {
        k_mlp<<<N_EDGES/256, 256, 0, stream>>>(ea, perm, fcw1, fcw2, fcw3, wq);
        k2_gather<<<(N_NODES + 3)/4, 256, 0, stream>>>(
            esh, eidx, perm, start, wq, ys, yv, ns, nv);
    } else {
        k2_seg<<<(N_NODES + 3)/4, 256, 0, stream>>>(
            ea, esh, eidx, perm, start, fcw1, fcw2, fcw3, ys, yv, ns, nv);
    }

    k3_node_post<<<(N_NODES + 31)/32, 256, 0, stream>>>(
        ns, nv, start, w2s, w2v, scs, scv, gs, gv, out);
}

// Round 4
// 376.923 us; speedup vs baseline: 4.3985x; 1.3329x over previous
//
#include <hip/hip_runtime.h>
#include <math.h>

#define N_NODES 20000
#define N_EDGES 320000

typedef __attribute__((ext_vector_type(8))) short bf16x8;
typedef __attribute__((ext_vector_type(4))) float f32x4;
typedef __attribute__((ext_vector_type(2))) unsigned u32x2;
typedef __attribute__((ext_vector_type(4))) unsigned u32x4;

__device__ __forceinline__ float silu_f(float x) {
    return x / (1.0f + __expf(-x));
}
__device__ __forceinline__ short f2bf(float x) {
    union { float f; unsigned u; } v; v.f = x;
    unsigned r = (v.u + 0x7FFFu + ((v.u >> 16) & 1u)) >> 16;
    return (short)r;
}
__device__ __forceinline__ float bf2f(short h) {
    union { unsigned u; float f; } v; v.u = ((unsigned)(unsigned short)h) << 16;
    return v.f;
}
// packed f32x2 -> bf16x2 (RNE), 1 instr
__device__ __forceinline__ unsigned cvt_pk(float lo, float hi) {
    unsigned r;
    asm("v_cvt_pk_bf16_f32 %0, %1, %2" : "=v"(r) : "v"(lo), "v"(hi));
    return r;
}
__device__ __forceinline__ float rlane(float v, int l) {
    return __uint_as_float(__builtin_amdgcn_readlane(__float_as_uint(v), l));
}

// ---------------- sort pass ----------------
__global__ __launch_bounds__(256) void s_hist(const int* __restrict__ eidx,
                                              int* __restrict__ cnt) {
    const int e = blockIdx.x * 256 + threadIdx.x;
    if (e < N_EDGES) atomicAdd(&cnt[eidx[e]], 1);
}

// single block, 1024 thr, 20 elems/thread; writes start[] and cursor into cnt[]
__global__ __launch_bounds__(1024) void s_scan(int* __restrict__ cnt,
                                               int* __restrict__ start) {
    const int tid = threadIdx.x;
    const int base = tid * 20;
    int vals[20];
    int sum = 0;
    #pragma unroll
    for (int j = 0; j < 20; ++j) {
        const int i = base + j;
        const int v = (i < N_NODES) ? cnt[i] : 0;
        vals[j] = sum;            // local exclusive
        sum += v;
    }
    const int lane = tid & 63, wv = tid >> 6;
    int x = sum;
    #pragma unroll
    for (int off = 1; off < 64; off <<= 1) {
        const int t = __shfl_up(x, off);
        if (lane >= off) x += t;
    }
    __shared__ int wtot[16];
    if (lane == 63) wtot[wv] = x;
    __syncthreads();
    int wpref = 0;
    for (int k = 0; k < wv; ++k) wpref += wtot[k];
    const int excl = wpref + x - sum;
    #pragma unroll
    for (int j = 0; j < 20; ++j) {
        const int i = base + j;
        if (i < N_NODES) {
            const int s = excl + vals[j];
            start[i] = s;
            cnt[i] = s;          // cnt doubles as cursor
        }
    }
    if (tid == 1023) start[N_NODES] = wpref + x;
}

__global__ __launch_bounds__(256) void s_scatter(const int* __restrict__ eidx,
                                                 int* __restrict__ cursor,
                                                 int* __restrict__ perm) {
    const int e = blockIdx.x * 256 + threadIdx.x;
    if (e >= N_EDGES) return;
    const int src = eidx[e];
    const int pos = atomicAdd(&cursor[src], 1);
    perm[pos] = e;
}

// ---------------- weight prepack (once, tiny) ----------------
// Fragment-direct layouts for mfma_f32_16x16x32_bf16 operand A (row=l15, k=lhi*8+j).
__global__ __launch_bounds__(256) void k_pack(
    const float* __restrict__ fcw1, const float* __restrict__ fcw2,
    const float* __restrict__ fcw3,
    short* __restrict__ w1A, short* __restrict__ w2A, short* __restrict__ w3A)
{
    const int tid = blockIdx.x * 256 + threadIdx.x;
    const int nthr = gridDim.x * 256;
    for (int i = tid; i < 4*64*8; i += nthr) {           // W1^T, K padded to 32
        const int j = i & 7, lane = (i >> 3) & 63, t = i >> 9;
        const int k = (lane >> 4) * 8 + j, row = t*16 + (lane & 15);
        w1A[i] = (k < 8) ? f2bf(fcw1[k*64 + row]) : (short)0;
    }
    for (int i = tid; i < 8*64*8; i += nthr) {           // W2^T [t][kk][lane][8]
        const int j = i & 7, lane = (i >> 3) & 63, kk = (i >> 9) & 1, t = i >> 10;
        const int k = kk*32 + (lane >> 4)*8 + j, row = t*16 + (lane & 15);
        w2A[i] = f2bf(fcw2[k*64 + row]);
    }
    for (int i = tid; i < 32*64*8; i += nthr) {          // W3^T [T][kk][lane][8]
        const int j = i & 7, lane = (i >> 3) & 63, kk = (i >> 9) & 1, T = i >> 10;
        const int k = kk*32 + (lane >> 4)*8 + j, c = T*16 + (lane & 15);
        w3A[i] = f2bf(fcw3[(size_t)k*256 + c]);
    }
}

// ---------------- K1: node pre-GEMMs (packed outputs) ----------------
__global__ __launch_bounds__(256) void k1_node_pre(
    const float* __restrict__ nh,
    const float* __restrict__ w1s, const float* __restrict__ w1v,
    const float* __restrict__ wscs, const float* __restrict__ wscv,
    float* __restrict__ ydata, float* __restrict__ scpack)
{
    __shared__ float lw1s[64*64], lw1v[64*64], lwscs[64*64], lwscv[64*64];
    for (int i = threadIdx.x; i < 64*64; i += 256) {
        lw1s[i] = w1s[i]; lw1v[i] = w1v[i];
        lwscs[i] = wscs[i]; lwscv[i] = wscv[i];
    }
    __syncthreads();
    const int wave = threadIdx.x >> 6, lane = threadIdx.x & 63;
    const int base = blockIdx.x * 32 + wave * 8;
    for (int ni = 0; ni < 8; ++ni) {
        const int n = base + ni;
        if (n >= N_NODES) break;
        const float* row = nh + (size_t)n * 256;
        const float xs  = row[lane];
        const float xv0 = row[64 + lane*3 + 0];
        const float xv1 = row[64 + lane*3 + 1];
        const float xv2 = row[64 + lane*3 + 2];
        float a_ys = 0.f, a_ss = 0.f;
        float a_v0 = 0.f, a_v1 = 0.f, a_v2 = 0.f;
        float a_s0 = 0.f, a_s1 = 0.f, a_s2 = 0.f;
        #pragma unroll 8
        for (int u = 0; u < 64; ++u) {
            const float xsu  = rlane(xs, u);
            const float x0u  = rlane(xv0, u);
            const float x1u  = rlane(xv1, u);
            const float x2u  = rlane(xv2, u);
            const float w1   = lw1s[u*64 + lane];
            const float wv   = lw1v[u*64 + lane];
            const float wss  = lwscs[u*64 + lane];
            const float wsv  = lwscv[u*64 + lane];
            a_ys += xsu * w1;   a_ss += xsu * wss;
            a_v0 += x0u * wv;   a_v1 += x1u * wv;   a_v2 += x2u * wv;
            a_s0 += x0u * wsv;  a_s1 += x1u * wsv;  a_s2 += x2u * wsv;
        }
        const float inv = 0.125f;
        float4 yo = { a_ys*inv, a_v0*inv, a_v1*inv, a_v2*inv };
        float4 so = { a_ss*inv, a_s0*inv, a_s1*inv, a_s2*inv };
        *(float4*)(ydata  + ((size_t)n*64 + lane)*4) = yo;
        *(float4*)(scpack + ((size_t)n*64 + lane)*4) = so;
    }
}

// ---------------- K_mlp: MFMA edge MLP, operand-swapped (h^T) ----------------
// Per wave: 64 edges (4 sub-tiles of 16). LDS h-buffers per wave, byte-swizzled.
// wq layout: [slot][q=4][v=64] bf16.
__global__ __launch_bounds__(256) void k_mlp(
    const float* __restrict__ ea, const int* __restrict__ perm,
    const short* __restrict__ w1A, const short* __restrict__ w2A,
    const short* __restrict__ w3A, short* __restrict__ wq)
{
    __shared__ short hb1[4][1024];
    __shared__ short hb2[4][1024];
    const int lane = threadIdx.x & 63, w = threadIdx.x >> 6;
    const int l15 = lane & 15, lhi = lane >> 4;
    const int wbase = (blockIdx.x * 4 + w) * 64;
    short* h1b = hb1[w];
    short* h2b = hb2[w];
    const int swz = (l15 & 7) << 4;   // byte XOR, 16B granular
    const f32x4 zz = {0.f, 0.f, 0.f, 0.f};

    bf16x8 a1[4], a2[4][2];
    #pragma unroll
    for (int t = 0; t < 4; ++t)
        a1[t] = *(const bf16x8*)&w1A[(t*64 + lane)*8];
    #pragma unroll
    for (int t = 0; t < 4; ++t)
        #pragma unroll
        for (int kk = 0; kk < 2; ++kk)
            a2[t][kk] = *(const bf16x8*)&w2A[((t*2 + kk)*64 + lane)*8];

    bf16x8 bh2[4][2];
    for (int sb = 0; sb < 4; ++sb) {
        // ---- B = ea^T: lanes lhi==0 carry k=0..7 for edge=l15 ----
        bf16x8 bea = {0,0,0,0,0,0,0,0};
        if (lhi == 0) {
            const int e = perm[wbase + sb*16 + l15];
            const float4 p0 = *(const float4*)(ea + (size_t)e*8);
            const float4 p1 = *(const float4*)(ea + (size_t)e*8 + 4);
            union { u32x4 u; bf16x8 v; } tu;
            tu.u[0] = cvt_pk(p0.x, p0.y);
            tu.u[1] = cvt_pk(p0.z, p0.w);
            tu.u[2] = cvt_pk(p1.x, p1.y);
            tu.u[3] = cvt_pk(p1.z, p1.w);
            bea = tu.v;
        }
        // ---- L1: h1^T = silu(W1^T . ea^T * c1) ----
        f32x4 d1[4];
        #pragma unroll
        for (int t = 0; t < 4; ++t)
            d1[t] = __builtin_amdgcn_mfma_f32_16x16x32_bf16(a1[t], bea, zz, 0,0,0);
        #pragma unroll
        for (int t = 0; t < 4; ++t) {
            const float s0 = silu_f(d1[t][0] * 0.35355339059327373f);
            const float s1 = silu_f(d1[t][1] * 0.35355339059327373f);
            const float s2 = silu_f(d1[t][2] * 0.35355339059327373f);
            const float s3 = silu_f(d1[t][3] * 0.35355339059327373f);
            u32x2 pk; pk[0] = cvt_pk(s0, s1); pk[1] = cvt_pk(s2, s3);
            const int byt = (l15*128 + t*32 + lhi*8) ^ swz;
            *(u32x2*)((char*)h1b + byt) = pk;
        }
        // ---- L2 ----
        bf16x8 bh1[2];
        #pragma unroll
        for (int kk = 0; kk < 2; ++kk)
            bh1[kk] = *(const bf16x8*)((const char*)h1b + ((l15*128 + kk*64 + lhi*16) ^ swz));
        f32x4 d2[4];
        #pragma unroll
        for (int t = 0; t < 4; ++t) {
            d2[t] = __builtin_amdgcn_mfma_f32_16x16x32_bf16(a2[t][0], bh1[0], zz, 0,0,0);
            d2[t] = __builtin_amdgcn_mfma_f32_16x16x32_bf16(a2[t][1], bh1[1], d2[t], 0,0,0);
        }
        #pragma unroll
        for (int t = 0; t < 4; ++t) {
            const float s0 = silu_f(d2[t][0] * 0.125f) * 0.125f;  // fold final 1/8
            const float s1 = silu_f(d2[t][1] * 0.125f) * 0.125f;
            const float s2 = silu_f(d2[t][2] * 0.125f) * 0.125f;
            const float s3 = silu_f(d2[t][3] * 0.125f) * 0.125f;
            u32x2 pk; pk[0] = cvt_pk(s0, s1); pk[1] = cvt_pk(s2, s3);
            const int byt = (l15*128 + t*32 + lhi*8) ^ swz;
            *(u32x2*)((char*)h2b + byt) = pk;
        }
        #pragma unroll
        for (int kk = 0; kk < 2; ++kk)
            bh2[sb][kk] = *(const bf16x8*)((const char*)h2b + ((l15*128 + kk*64 + lhi*16) ^ swz));
    }

    // ---- L3: w^T = W3^T . h2^T ; store packed [slot][q][v] ----
    for (int T = 0; T < 16; ++T) {
        bf16x8 a3[2];
        a3[0] = *(const bf16x8*)&w3A[((T*2 + 0)*64 + lane)*8];
        a3[1] = *(const bf16x8*)&w3A[((T*2 + 1)*64 + lane)*8];
        const int q = T >> 2;
        const int vb = (T & 3)*16 + lhi*4;
        #pragma unroll
        for (int sb = 0; sb < 4; ++sb) {
            f32x4 d = __builtin_amdgcn_mfma_f32_16x16x32_bf16(a3[0], bh2[sb][0], zz, 0,0,0);
            d = __builtin_amdgcn_mfma_f32_16x16x32_bf16(a3[1], bh2[sb][1], d, 0,0,0);
            u32x2 pk; pk[0] = cvt_pk(d[0], d[1]); pk[1] = cvt_pk(d[2], d[3]);
            const int slot = wbase + sb*16 + l15;
            *(u32x2*)&wq[(size_t)(slot*4 + q)*64 + vb] = pk;
        }
    }
}

// ---------------- K2: per-node gather + register segment-sum ----------------
__global__ __launch_bounds__(256) void k2_gather(
    const float* __restrict__ esh, const int* __restrict__ eidx,
    const int* __restrict__ perm, const int* __restrict__ start,
    const short* __restrict__ wq, const float* __restrict__ ydata,
    float* __restrict__ ncat)
{
    const int lane = threadIdx.x & 63;
    const int n = blockIdx.x * 4 + (threadIdx.x >> 6);
    if (n >= N_NODES) return;
    const int s0 = start[n], s1 = start[n + 1];
    float acc0=0.f, acc1=0.f, av0=0.f, av1=0.f, av2=0.f, bv0=0.f, bv1=0.f, bv2=0.f;
    for (int p = s0; p < s1; p += 4) {
        const int m = s1 - p;  // wave-uniform
        float wa[4], wb[4], wc[4], wd[4];
        float4 sh[4], yd[4];
        #pragma unroll
        for (int j = 0; j < 4; ++j) {
            const int pp = (j < m) ? p + j : s0;
            const int e = __builtin_amdgcn_readfirstlane(perm[pp]);
            const size_t wbo = (size_t)pp * 256;
            wa[j] = bf2f(wq[wbo + lane]);
            wb[j] = bf2f(wq[wbo +  64 + lane]);
            wc[j] = bf2f(wq[wbo + 128 + lane]);
            wd[j] = bf2f(wq[wbo + 192 + lane]);
            sh[j] = *(const float4*)(esh + (size_t)e*4);
            const int dst = eidx[N_EDGES + e];
            yd[j] = *(const float4*)(ydata + ((size_t)dst*64 + lane)*4);
        }
        #pragma unroll
        for (int j = 0; j < 4; ++j) {
            const float g = (j < m) ? 1.f : 0.f;
            const float wa_ = wa[j]*g, wb_ = wb[j]*g, wc_ = wc[j]*g, wd_ = wd[j]*g;
            const float es = yd[j].x, ev0 = yd[j].y, ev1 = yd[j].z, ev2 = yd[j].w;
            acc0 += wa_ * es * sh[j].x;
            acc1 += wd_ * (ev0*sh[j].y + ev1*sh[j].z + ev2*sh[j].w) * 0.5773502691896258f;
            const float esb = wb_ * es;
            av0 += esb * sh[j].y; av1 += esb * sh[j].z; av2 += esb * sh[j].w;
            const float c0 = wc_ * sh[j].x;
            bv0 += c0 * ev0; bv1 += c0 * ev1; bv2 += c0 * ev2;
        }
    }
    float* nrow = ncat + ((size_t)n*64 + lane)*8;
    float4 o0 = { acc0, acc1, av0, av1 };
    float4 o1 = { av2, bv0, bv1, bv2 };
    *(float4*)(nrow)     = o0;
    *(float4*)(nrow + 4) = o1;
}

// ---------------- fallback K2 (packed layouts) ----------------
__global__ __launch_bounds__(256) void k2_seg(
    const float* __restrict__ ea, const float* __restrict__ esh,
    const int* __restrict__ eidx, const int* __restrict__ perm,
    const int* __restrict__ start,
    const float* __restrict__ fcw1, const float* __restrict__ fcw2,
    const float* __restrict__ fcw3,
    const float* __restrict__ ydata, float* __restrict__ ncat)
{
    __shared__ float lw1[8*64];
    __shared__ float lw2[64*64];
    for (int i = threadIdx.x; i < 8*64; i += 256)  lw1[i] = fcw1[i];
    for (int i = threadIdx.x; i < 64*64; i += 256) lw2[i] = fcw2[i];
    __syncthreads();
    const int lane = threadIdx.x & 63;
    const int n = blockIdx.x * 4 + (threadIdx.x >> 6);
    if (n >= N_NODES) return;
    const int s0 = start[n], s1 = start[n + 1];
    float acc0=0.f, acc1=0.f, av0=0.f, av1=0.f, av2=0.f, bv0=0.f, bv1=0.f, bv2=0.f;
    for (int p = s0; p < s1; p += 4) {
        int idx[4];
        float h1[4];
        #pragma unroll
        for (int j = 0; j < 4; ++j) {
            const bool ok = (p + j < s1);
            idx[j] = perm[ok ? p + j : p];
            const float* eap = ea + (size_t)idx[j] * 8;
            float a = 0.f;
            #pragma unroll
            for (int u = 0; u < 8; ++u) a += eap[u] * lw1[u*64 + lane];
            a = ok ? a * 0.35355339059327373f : 0.f;
            h1[j] = silu_f(a);
        }
        float h2[4] = {0.f, 0.f, 0.f, 0.f};
        #pragma unroll 8
        for (int u = 0; u < 64; ++u) {
            const float wv = lw2[u*64 + lane];
            h2[0] += rlane(h1[0], u) * wv;
            h2[1] += rlane(h1[1], u) * wv;
            h2[2] += rlane(h1[2], u) * wv;
            h2[3] += rlane(h1[3], u) * wv;
        }
        #pragma unroll
        for (int j = 0; j < 4; ++j) h2[j] = silu_f(h2[j] * 0.125f) * 0.125f;
        float wa[4] = {0,0,0,0}, wb[4] = {0,0,0,0}, wc[4] = {0,0,0,0}, wd[4] = {0,0,0,0};
        #pragma unroll 4
        for (int u = 0; u < 64; ++u) {
            const float* r = fcw3 + u * 256;
            const float r0 = r[lane], r1 = r[64 + lane], r2 = r[128 + lane], r3 = r[192 + lane];
            #pragma unroll
            for (int j = 0; j < 4; ++j) {
                const float hu = rlane(h2[j], u);
                wa[j] += hu * r0; wb[j] += hu * r1; wc[j] += hu * r2; wd[j] += hu * r3;
            }
        }
        #pragma unroll
        for (int j = 0; j < 4; ++j) {
            const int e = idx[j];
            const int dst = eidx[N_EDGES + e];
            const float4 sh = *(const float4*)(esh + (size_t)e*4);
            const float4 yd = *(const float4*)(ydata + ((size_t)dst*64 + lane)*4);
            acc0 += wa[j] * yd.x * sh.x;
            acc1 += wd[j] * (yd.y*sh.y + yd.z*sh.z + yd.w*sh.w) * 0.5773502691896258f;
            const float esb = wb[j] * yd.x;
            av0 += esb * sh.y; av1 += esb * sh.z; av2 += esb * sh.w;
            const float c0 = wc[j] * sh.x;
            bv0 += c0 * yd.y; bv1 += c0 * yd.z; bv2 += c0 * yd.w;
        }
    }
    float* nrow = ncat + ((size_t)n*64 + lane)*8;
    float4 o0 = { acc0, acc1, av0, av1 };
    float4 o1 = { av2, bv0, bv1, bv2 };
    *(float4*)(nrow)     = o0;
    *(float4*)(nrow + 4) = o1;
}

// ---------------- K3: node post-GEMM + RMS norm ----------------
__global__ __launch_bounds__(256) void k3_node_post(
    const float* __restrict__ ncat, const int* __restrict__ start,
    const float* __restrict__ w2s, const float* __restrict__ w2v,
    const float* __restrict__ scpack,
    const float* __restrict__ gs, const float* __restrict__ gv,
    float* __restrict__ out)
{
    __shared__ float lw2s[128*64], lw2v[128*64];
    for (int i = threadIdx.x; i < 128*64; i += 256) {
        lw2s[i] = w2s[i]; lw2v[i] = w2v[i];
    }
    __syncthreads();
    const int wave = threadIdx.x >> 6, lane = threadIdx.x & 63;
    const int base = blockIdx.x * 32 + wave * 8;
    for (int ni = 0; ni < 8; ++ni) {
        const int n = base + ni;
        if (n >= N_NODES) break;
        const float* nrow = ncat + ((size_t)n*64 + lane)*8;
        const float4 r0 = *(const float4*)(nrow);
        const float4 r1 = *(const float4*)(nrow + 4);
        const float ns0 = r0.x, ns1 = r0.y;
        const float nva0 = r0.z, nva1 = r0.w, nva2 = r1.x;
        const float nvb0 = r1.y, nvb1 = r1.z, nvb2 = r1.w;
        float aos = 0.f, a0 = 0.f, a1 = 0.f, a2 = 0.f;
        #pragma unroll 8
        for (int u = 0; u < 64; ++u) {
            const float nsu = rlane(ns0, u);
            const float v0u = rlane(nva0, u);
            const float v1u = rlane(nva1, u);
            const float v2u = rlane(nva2, u);
            const float ws = lw2s[u*64 + lane];
            const float wv = lw2v[u*64 + lane];
            aos += nsu * ws;
            a0 += v0u * wv;  a1 += v1u * wv;  a2 += v2u * wv;
        }
        #pragma unroll 8
        for (int u = 0; u < 64; ++u) {
            const float nsu = rlane(ns1, u);
            const float v0u = rlane(nvb0, u);
            const float v1u = rlane(nvb1, u);
            const float v2u = rlane(nvb2, u);
            const float ws = lw2s[(64+u)*64 + lane];
            const float wv = lw2v[(64+u)*64 + lane];
            aos += nsu * ws;
            a0 += v0u * wv;  a1 += v1u * wv;  a2 += v2u * wv;
        }
        const float degf = (float)(start[n+1] - start[n]);
        const float dn = rsqrtf(fmaxf(degf, 1.0f));
        const float inv2 = 0.08838834764831845f;
        const float4 sc = *(const float4*)(scpack + ((size_t)n*64 + lane)*4);
        float os  = aos * inv2 * dn + sc.x;
        float ov0 = a0  * inv2 * dn + sc.y;
        float ov1 = a1  * inv2 * dn + sc.z;
        float ov2 = a2  * inv2 * dn + sc.w;

        float ssq = os * os;
        #pragma unroll
        for (int off = 32; off; off >>= 1) ssq += __shfl_xor(ssq, off);
        os *= rsqrtf(ssq * (1.0f/64.0f) + 1e-5f) * gs[lane];

        float vsq = ov0*ov0 + ov1*ov1 + ov2*ov2;
        #pragma unroll
        for (int off = 32; off; off >>= 1) vsq += __shfl_xor(vsq, off);
        const float rv = rsqrtf(vsq * (1.0f/192.0f) + 1e-5f) * gv[lane];
        ov0 *= rv; ov1 *= rv; ov2 *= rv;

        float* orow = out + (size_t)n * 256;
        orow[lane] = os;
        orow[64 + lane*3 + 0] = ov0;
        orow[64 + lane*3 + 1] = ov1;
        orow[64 + lane*3 + 2] = ov2;
    }
}

extern "C" void kernel_launch(void* const* d_in, const int* in_sizes, int n_in,
                              void* d_out, int out_size, void* d_ws, size_t ws_size,
                              hipStream_t stream) {
    const float* nh   = (const float*)d_in[0];
    const float* ea   = (const float*)d_in[1];
    const float* esh  = (const float*)d_in[2];
    const float* w1s  = (const float*)d_in[3];
    const float* w1v  = (const float*)d_in[4];
    const float* wscs = (const float*)d_in[5];
    const float* wscv = (const float*)d_in[6];
    const float* w2s  = (const float*)d_in[7];
    const float* w2v  = (const float*)d_in[8];
    const float* fcw1 = (const float*)d_in[9];
    const float* fcw2 = (const float*)d_in[10];
    const float* fcw3 = (const float*)d_in[11];
    const float* gs   = (const float*)d_in[12];
    const float* gv   = (const float*)d_in[13];
    const int*   eidx = (const int*)d_in[14];
    float* out = (float*)d_out;

    float* wsf = (float*)d_ws;
    size_t off = 0;
    float* ydata  = wsf + off; off += (size_t)N_NODES * 64 * 4;
    float* scpack = wsf + off; off += (size_t)N_NODES * 64 * 4;
    float* ncat   = wsf + off; off += (size_t)N_NODES * 64 * 8;
    int* ibase  = (int*)(wsf + off);
    int* cnt    = ibase;                      // doubles as cursor after scan
    int* start  = ibase + N_NODES;            // N_NODES+1
    int* perm   = ibase + 2*N_NODES + 1;      // N_EDGES
    short* w1A = (short*)(ibase + 2*N_NODES + 1 + N_EDGES);
    short* w2A = w1A + 4*64*8;
    short* w3A = w2A + 8*64*8;
    size_t used = (size_t)((char*)(w3A + 32*64*8) - (char*)d_ws);
    size_t wq_off = (used + 15) & ~(size_t)15;
    short* wq = (short*)((char*)d_ws + wq_off);
    const size_t need = wq_off + (size_t)N_EDGES * 256 * 2;

    hipMemsetAsync(cnt, 0, N_NODES * sizeof(int), stream);

    s_hist<<<(N_EDGES + 255)/256, 256, 0, stream>>>(eidx, cnt);
    s_scan<<<1, 1024, 0, stream>>>(cnt, start);
    s_scatter<<<(N_EDGES + 255)/256, 256, 0, stream>>>(eidx, cnt, perm);

    k1_node_pre<<<(N_NODES + 31)/32, 256, 0, stream>>>(
        nh, w1s, w1v, wscs, wscv, ydata, scpack);

    if (ws_size >= need) {
        k_pack<<<32, 256, 0, stream>>>(fcw1, fcw2, fcw3, w1A, w2A, w3A);
        k_mlp<<<N_EDGES/256, 256, 0, stream>>>(ea, perm, w1A, w2A, w3A, wq);
        k2_gather<<<(N_NODES + 3)/4, 256, 0, stream>>>(
            esh, eidx, perm, start, wq, ydata, ncat);
    } else {
        k2_seg<<<(N_NODES + 3)/4, 256, 0, stream>>>(
            ea, esh, eidx, perm, start, fcw1, fcw2, fcw3, ydata, ncat);
    }

    k3_node_post<<<(N_NODES + 31)/32, 256, 0, stream>>>(
        ncat, start, w2s, w2v, scpack, gs, gv, out);
}

// Round 5
// 276.197 us; speedup vs baseline: 6.0027x; 1.3647x over previous
//
#include <hip/hip_runtime.h>
#include <math.h>

#define N_NODES 20000
#define N_EDGES 320000
#define N_TILES 1250   // N_NODES / 16

typedef __attribute__((ext_vector_type(8))) short bf16x8;
typedef __attribute__((ext_vector_type(4))) float f32x4;
typedef __attribute__((ext_vector_type(2))) unsigned u32x2;
typedef __attribute__((ext_vector_type(4))) unsigned u32x4;

__device__ __forceinline__ float silu_f(float x) {
    return x / (1.0f + __expf(-x));
}
__device__ __forceinline__ short f2bf(float x) {
    union { float f; unsigned u; } v; v.f = x;
    unsigned r = (v.u + 0x7FFFu + ((v.u >> 16) & 1u)) >> 16;
    return (short)r;
}
__device__ __forceinline__ float bf2f(short h) {
    union { unsigned u; float f; } v; v.u = ((unsigned)(unsigned short)h) << 16;
    return v.f;
}
__device__ __forceinline__ unsigned cvt_pk(float lo, float hi) {
    unsigned r;
    asm("v_cvt_pk_bf16_f32 %0, %1, %2" : "=v"(r) : "v"(lo), "v"(hi));
    return r;
}
__device__ __forceinline__ float rlane(float v, int l) {
    return __uint_as_float(__builtin_amdgcn_readlane(__float_as_uint(v), l));
}
#define MFMA16(a, b, c) __builtin_amdgcn_mfma_f32_16x16x32_bf16((a), (b), (c), 0, 0, 0)

// ---------------- sort pass ----------------
__global__ __launch_bounds__(256) void s_hist(const int* __restrict__ eidx,
                                              int* __restrict__ cnt) {
    const int e = blockIdx.x * 256 + threadIdx.x;
    if (e < N_EDGES) atomicAdd(&cnt[eidx[e]], 1);
}

__global__ __launch_bounds__(1024) void s_scan(int* __restrict__ cnt,
                                               int* __restrict__ start) {
    const int tid = threadIdx.x;
    const int base = tid * 20;
    int vals[20];
    int sum = 0;
    #pragma unroll
    for (int j = 0; j < 20; ++j) {
        const int i = base + j;
        const int v = (i < N_NODES) ? cnt[i] : 0;
        vals[j] = sum;
        sum += v;
    }
    const int lane = tid & 63, wv = tid >> 6;
    int x = sum;
    #pragma unroll
    for (int off = 1; off < 64; off <<= 1) {
        const int t = __shfl_up(x, off);
        if (lane >= off) x += t;
    }
    __shared__ int wtot[16];
    if (lane == 63) wtot[wv] = x;
    __syncthreads();
    int wpref = 0;
    for (int k = 0; k < wv; ++k) wpref += wtot[k];
    const int excl = wpref + x - sum;
    #pragma unroll
    for (int j = 0; j < 20; ++j) {
        const int i = base + j;
        if (i < N_NODES) {
            const int s = excl + vals[j];
            start[i] = s;
            cnt[i] = s;   // cnt doubles as cursor
        }
    }
    if (tid == 1023) start[N_NODES] = wpref + x;
}

__global__ __launch_bounds__(256) void s_scatter(const int* __restrict__ eidx,
                                                 const float* __restrict__ esh,
                                                 int* __restrict__ cursor,
                                                 int* __restrict__ perm,
                                                 int* __restrict__ dst_perm,
                                                 float* __restrict__ esh_perm) {
    const int e = blockIdx.x * 256 + threadIdx.x;
    if (e >= N_EDGES) return;
    const int src = eidx[e];
    const int pos = atomicAdd(&cursor[src], 1);
    perm[pos] = e;
    dst_perm[pos] = eidx[N_EDGES + e];
    *(float4*)(esh_perm + (size_t)pos * 4) = *(const float4*)(esh + (size_t)e * 4);
}

// ---------------- weight prepack ----------------
// A-fragment layout for mfma_f32_16x16x32_bf16: A[row][k], row=out-channel,
// frag short index = ((vt*KT + kk)*64 + lane)*8 + j ; row=vt*16+(lane&15),
// k = kk*32 + (lane>>4)*8 + j.
__global__ __launch_bounds__(256) void k_pack(
    const float* __restrict__ fcw1, const float* __restrict__ fcw2,
    const float* __restrict__ fcw3,
    const float* __restrict__ w1s, const float* __restrict__ wscs,
    const float* __restrict__ w1v, const float* __restrict__ wscv,
    const float* __restrict__ w2s, const float* __restrict__ w2v,
    short* __restrict__ w1A, short* __restrict__ w2A, short* __restrict__ w3A,
    short* __restrict__ wp1, short* __restrict__ wp2)
{
    const int tid = blockIdx.x * 256 + threadIdx.x;
    const int nthr = gridDim.x * 256;
    for (int i = tid; i < 4*64*8; i += nthr) {           // fc_w1^T, K padded
        const int j = i & 7, lane = (i >> 3) & 63, t = i >> 9;
        const int k = (lane >> 4) * 8 + j, row = t*16 + (lane & 15);
        w1A[i] = (k < 8) ? f2bf(fcw1[k*64 + row]) : (short)0;
    }
    for (int i = tid; i < 8*64*8; i += nthr) {           // fc_w2^T
        const int j = i & 7, lane = (i >> 3) & 63, kk = (i >> 9) & 1, t = i >> 10;
        const int k = kk*32 + (lane >> 4)*8 + j, row = t*16 + (lane & 15);
        w2A[i] = f2bf(fcw2[k*64 + row]);
    }
    for (int i = tid; i < 32*64*8; i += nthr) {          // fc_w3^T
        const int j = i & 7, lane = (i >> 3) & 63, kk = (i >> 9) & 1, T = i >> 10;
        const int k = kk*32 + (lane >> 4)*8 + j, c = T*16 + (lane & 15);
        w3A[i] = f2bf(fcw3[(size_t)k*256 + c]);
    }
    for (int i = tid; i < 4096; i += nthr) {             // k1 weights (64x64)
        const int j = i & 7, lane = (i >> 3) & 63, kk = (i >> 9) & 1, vt = i >> 10;
        const int row = vt*16 + (lane & 15), k = kk*32 + (lane >> 4)*8 + j;
        wp1[i]         = f2bf(w1s [k*64 + row]);
        wp1[4096 + i]  = f2bf(wscs[k*64 + row]);
        wp1[8192 + i]  = f2bf(w1v [k*64 + row]);
        wp1[12288 + i] = f2bf(wscv[k*64 + row]);
    }
    for (int i = tid; i < 8192; i += nthr) {             // k3 weights (128x64)
        const int j = i & 7, lane = (i >> 3) & 63, kk = (i >> 9) & 3, vt = i >> 11;
        const int row = vt*16 + (lane & 15), k = kk*32 + (lane >> 4)*8 + j;
        wp2[i]        = f2bf(w2s[k*64 + row]);
        wp2[8192 + i] = f2bf(w2v[k*64 + row]);
    }
}

// ---------------- K1: node pre-GEMMs via MFMA (operand-swapped) ----------------
__global__ __launch_bounds__(256) void k1_mfma(
    const float* __restrict__ nh, const short* __restrict__ wp1,
    float* __restrict__ ydata, float* __restrict__ scpack)
{
    const int lane = threadIdx.x & 63;
    const int tile = blockIdx.x * 4 + (threadIdx.x >> 6);
    if (tile >= N_TILES) return;
    const int l15 = lane & 15, lhi = lane >> 4;
    const int n = tile*16 + l15;
    const float* row = nh + (size_t)n * 256;
    const f32x4 zz = {0.f, 0.f, 0.f, 0.f};
    f32x4 acc[8][4];
    #pragma unroll
    for (int c = 0; c < 8; ++c)
        #pragma unroll
        for (int vt = 0; vt < 4; ++vt) acc[c][vt] = zz;

    #pragma unroll
    for (int kk = 0; kk < 2; ++kk) {
        const int k0 = kk*32 + lhi*8;
        const float4 s0 = *(const float4*)(row + k0);
        const float4 s1 = *(const float4*)(row + k0 + 4);
        float4 vv[6];
        #pragma unroll
        for (int q = 0; q < 6; ++q) vv[q] = *(const float4*)(row + 64 + 3*k0 + q*4);
        const float* vf = (const float*)vv;
        union { u32x4 u; bf16x8 v; } bs, b0, b1, b2;
        bs.u[0] = cvt_pk(s0.x, s0.y); bs.u[1] = cvt_pk(s0.z, s0.w);
        bs.u[2] = cvt_pk(s1.x, s1.y); bs.u[3] = cvt_pk(s1.z, s1.w);
        #pragma unroll
        for (int q = 0; q < 4; ++q) {
            b0.u[q] = cvt_pk(vf[6*q + 0], vf[6*q + 3]);
            b1.u[q] = cvt_pk(vf[6*q + 1], vf[6*q + 4]);
            b2.u[q] = cvt_pk(vf[6*q + 2], vf[6*q + 5]);
        }
        #pragma unroll
        for (int vt = 0; vt < 4; ++vt) {
            const int fo = ((vt*2 + kk)*64 + lane)*8;
            const bf16x8 a_ys = *(const bf16x8*)&wp1[fo];
            const bf16x8 a_ss = *(const bf16x8*)&wp1[4096 + fo];
            const bf16x8 a_yv = *(const bf16x8*)&wp1[8192 + fo];
            const bf16x8 a_sv = *(const bf16x8*)&wp1[12288 + fo];
            acc[0][vt] = MFMA16(a_ys, bs.v, acc[0][vt]);
            acc[1][vt] = MFMA16(a_ss, bs.v, acc[1][vt]);
            acc[2][vt] = MFMA16(a_yv, b0.v, acc[2][vt]);
            acc[3][vt] = MFMA16(a_yv, b1.v, acc[3][vt]);
            acc[4][vt] = MFMA16(a_yv, b2.v, acc[4][vt]);
            acc[5][vt] = MFMA16(a_sv, b0.v, acc[5][vt]);
            acc[6][vt] = MFMA16(a_sv, b1.v, acc[6][vt]);
            acc[7][vt] = MFMA16(a_sv, b2.v, acc[7][vt]);
        }
    }
    #pragma unroll
    for (int vt = 0; vt < 4; ++vt)
        #pragma unroll
        for (int r = 0; r < 4; ++r) {
            const int v = vt*16 + lhi*4 + r;
            const float4 yo = { acc[0][vt][r]*0.125f, acc[2][vt][r]*0.125f,
                                acc[3][vt][r]*0.125f, acc[4][vt][r]*0.125f };
            const float4 so = { acc[1][vt][r]*0.125f, acc[5][vt][r]*0.125f,
                                acc[6][vt][r]*0.125f, acc[7][vt][r]*0.125f };
            *(float4*)(ydata  + ((size_t)n*64 + v)*4) = yo;
            *(float4*)(scpack + ((size_t)n*64 + v)*4) = so;
        }
}

// ---------------- K_mlp: MFMA edge MLP (round-4, unchanged) ----------------
__global__ __launch_bounds__(256) void k_mlp(
    const float* __restrict__ ea, const int* __restrict__ perm,
    const short* __restrict__ w1A, const short* __restrict__ w2A,
    const short* __restrict__ w3A, short* __restrict__ wq)
{
    __shared__ short hb1[4][1024];
    __shared__ short hb2[4][1024];
    const int lane = threadIdx.x & 63, w = threadIdx.x >> 6;
    const int l15 = lane & 15, lhi = lane >> 4;
    const int wbase = (blockIdx.x * 4 + w) * 64;
    short* h1b = hb1[w];
    short* h2b = hb2[w];
    const int swz = (l15 & 7) << 4;
    const f32x4 zz = {0.f, 0.f, 0.f, 0.f};

    bf16x8 a1[4], a2[4][2];
    #pragma unroll
    for (int t = 0; t < 4; ++t)
        a1[t] = *(const bf16x8*)&w1A[(t*64 + lane)*8];
    #pragma unroll
    for (int t = 0; t < 4; ++t)
        #pragma unroll
        for (int kk = 0; kk < 2; ++kk)
            a2[t][kk] = *(const bf16x8*)&w2A[((t*2 + kk)*64 + lane)*8];

    bf16x8 bh2[4][2];
    for (int sb = 0; sb < 4; ++sb) {
        bf16x8 bea = {0,0,0,0,0,0,0,0};
        if (lhi == 0) {
            const int e = perm[wbase + sb*16 + l15];
            const float4 p0 = *(const float4*)(ea + (size_t)e*8);
            const float4 p1 = *(const float4*)(ea + (size_t)e*8 + 4);
            union { u32x4 u; bf16x8 v; } tu;
            tu.u[0] = cvt_pk(p0.x, p0.y);
            tu.u[1] = cvt_pk(p0.z, p0.w);
            tu.u[2] = cvt_pk(p1.x, p1.y);
            tu.u[3] = cvt_pk(p1.z, p1.w);
            bea = tu.v;
        }
        f32x4 d1[4];
        #pragma unroll
        for (int t = 0; t < 4; ++t)
            d1[t] = MFMA16(a1[t], bea, zz);
        #pragma unroll
        for (int t = 0; t < 4; ++t) {
            const float s0 = silu_f(d1[t][0] * 0.35355339059327373f);
            const float s1 = silu_f(d1[t][1] * 0.35355339059327373f);
            const float s2 = silu_f(d1[t][2] * 0.35355339059327373f);
            const float s3 = silu_f(d1[t][3] * 0.35355339059327373f);
            u32x2 pk; pk[0] = cvt_pk(s0, s1); pk[1] = cvt_pk(s2, s3);
            const int byt = (l15*128 + t*32 + lhi*8) ^ swz;
            *(u32x2*)((char*)h1b + byt) = pk;
        }
        bf16x8 bh1[2];
        #pragma unroll
        for (int kk = 0; kk < 2; ++kk)
            bh1[kk] = *(const bf16x8*)((const char*)h1b + ((l15*128 + kk*64 + lhi*16) ^ swz));
        f32x4 d2[4];
        #pragma unroll
        for (int t = 0; t < 4; ++t) {
            d2[t] = MFMA16(a2[t][0], bh1[0], zz);
            d2[t] = MFMA16(a2[t][1], bh1[1], d2[t]);
        }
        #pragma unroll
        for (int t = 0; t < 4; ++t) {
            const float s0 = silu_f(d2[t][0] * 0.125f) * 0.125f;
            const float s1 = silu_f(d2[t][1] * 0.125f) * 0.125f;
            const float s2 = silu_f(d2[t][2] * 0.125f) * 0.125f;
            const float s3 = silu_f(d2[t][3] * 0.125f) * 0.125f;
            u32x2 pk; pk[0] = cvt_pk(s0, s1); pk[1] = cvt_pk(s2, s3);
            const int byt = (l15*128 + t*32 + lhi*8) ^ swz;
            *(u32x2*)((char*)h2b + byt) = pk;
        }
        #pragma unroll
        for (int kk = 0; kk < 2; ++kk)
            bh2[sb][kk] = *(const bf16x8*)((const char*)h2b + ((l15*128 + kk*64 + lhi*16) ^ swz));
    }

    for (int T = 0; T < 16; ++T) {
        bf16x8 a3[2];
        a3[0] = *(const bf16x8*)&w3A[((T*2 + 0)*64 + lane)*8];
        a3[1] = *(const bf16x8*)&w3A[((T*2 + 1)*64 + lane)*8];
        const int q = T >> 2;
        const int vb = (T & 3)*16 + lhi*4;
        #pragma unroll
        for (int sb = 0; sb < 4; ++sb) {
            f32x4 d = MFMA16(a3[0], bh2[sb][0], zz);
            d = MFMA16(a3[1], bh2[sb][1], d);
            u32x2 pk; pk[0] = cvt_pk(d[0], d[1]); pk[1] = cvt_pk(d[2], d[3]);
            const int slot = wbase + sb*16 + l15;
            *(u32x2*)&wq[(size_t)(slot*4 + q)*64 + vb] = pk;
        }
    }
}

// ---------------- K2: per-node gather + register segment-sum ----------------
__global__ __launch_bounds__(256) void k2_gather(
    const int* __restrict__ start, const int* __restrict__ dst_perm,
    const float* __restrict__ esh_perm, const short* __restrict__ wq,
    const float* __restrict__ ydata, float* __restrict__ ncat)
{
    const int lane = threadIdx.x & 63;
    const int n = blockIdx.x * 4 + (threadIdx.x >> 6);
    if (n >= N_NODES) return;
    const int s0 = start[n], s1 = start[n + 1];
    float acc0=0.f, acc1=0.f, av0=0.f, av1=0.f, av2=0.f, bv0=0.f, bv1=0.f, bv2=0.f;
    for (int p = s0; p < s1; p += 4) {
        const int m = s1 - p;
        float wa[4], wb[4], wc[4], wd[4];
        float4 sh[4], yd[4];
        #pragma unroll
        for (int j = 0; j < 4; ++j) {
            const int pp = (j < m) ? p + j : s0;
            const size_t wbo = (size_t)pp * 256;
            wa[j] = bf2f(wq[wbo + lane]);
            wb[j] = bf2f(wq[wbo +  64 + lane]);
            wc[j] = bf2f(wq[wbo + 128 + lane]);
            wd[j] = bf2f(wq[wbo + 192 + lane]);
            sh[j] = *(const float4*)(esh_perm + (size_t)pp*4);
            const int dst = dst_perm[pp];
            yd[j] = *(const float4*)(ydata + ((size_t)dst*64 + lane)*4);
        }
        #pragma unroll
        for (int j = 0; j < 4; ++j) {
            const float g = (j < m) ? 1.f : 0.f;
            const float wa_ = wa[j]*g, wb_ = wb[j]*g, wc_ = wc[j]*g, wd_ = wd[j]*g;
            const float es = yd[j].x, ev0 = yd[j].y, ev1 = yd[j].z, ev2 = yd[j].w;
            acc0 += wa_ * es * sh[j].x;
            acc1 += wd_ * (ev0*sh[j].y + ev1*sh[j].z + ev2*sh[j].w) * 0.5773502691896258f;
            const float esb = wb_ * es;
            av0 += esb * sh[j].y; av1 += esb * sh[j].z; av2 += esb * sh[j].w;
            const float c0 = wc_ * sh[j].x;
            bv0 += c0 * ev0; bv1 += c0 * ev1; bv2 += c0 * ev2;
        }
    }
    float* nrow = ncat + ((size_t)n*64 + lane)*8;
    const float4 o0 = { acc0, av0, av1, av2 };
    const float4 o1 = { acc1, bv0, bv1, bv2 };
    *(float4*)(nrow)     = o0;
    *(float4*)(nrow + 4) = o1;
}

// ---------------- fallback K2 (no-wq path) ----------------
__global__ __launch_bounds__(256) void k2_seg(
    const float* __restrict__ ea, const float* __restrict__ esh,
    const int* __restrict__ eidx, const int* __restrict__ perm,
    const int* __restrict__ start,
    const float* __restrict__ fcw1, const float* __restrict__ fcw2,
    const float* __restrict__ fcw3,
    const float* __restrict__ ydata, float* __restrict__ ncat)
{
    __shared__ float lw1[8*64];
    __shared__ float lw2[64*64];
    for (int i = threadIdx.x; i < 8*64; i += 256)  lw1[i] = fcw1[i];
    for (int i = threadIdx.x; i < 64*64; i += 256) lw2[i] = fcw2[i];
    __syncthreads();
    const int lane = threadIdx.x & 63;
    const int n = blockIdx.x * 4 + (threadIdx.x >> 6);
    if (n >= N_NODES) return;
    const int s0 = start[n], s1 = start[n + 1];
    float acc0=0.f, acc1=0.f, av0=0.f, av1=0.f, av2=0.f, bv0=0.f, bv1=0.f, bv2=0.f;
    for (int p = s0; p < s1; p += 4) {
        int idx[4];
        float h1[4];
        #pragma unroll
        for (int j = 0; j < 4; ++j) {
            const bool ok = (p + j < s1);
            idx[j] = perm[ok ? p + j : p];
            const float* eap = ea + (size_t)idx[j] * 8;
            float a = 0.f;
            #pragma unroll
            for (int u = 0; u < 8; ++u) a += eap[u] * lw1[u*64 + lane];
            a = ok ? a * 0.35355339059327373f : 0.f;
            h1[j] = silu_f(a);
        }
        float h2[4] = {0.f, 0.f, 0.f, 0.f};
        #pragma unroll 8
        for (int u = 0; u < 64; ++u) {
            const float wv = lw2[u*64 + lane];
            h2[0] += rlane(h1[0], u) * wv;
            h2[1] += rlane(h1[1], u) * wv;
            h2[2] += rlane(h1[2], u) * wv;
            h2[3] += rlane(h1[3], u) * wv;
        }
        #pragma unroll
        for (int j = 0; j < 4; ++j) h2[j] = silu_f(h2[j] * 0.125f) * 0.125f;
        float wa[4] = {0,0,0,0}, wb[4] = {0,0,0,0}, wc[4] = {0,0,0,0}, wd[4] = {0,0,0,0};
        #pragma unroll 4
        for (int u = 0; u < 64; ++u) {
            const float* r = fcw3 + u * 256;
            const float r0 = r[lane], r1 = r[64 + lane], r2 = r[128 + lane], r3 = r[192 + lane];
            #pragma unroll
            for (int j = 0; j < 4; ++j) {
                const float hu = rlane(h2[j], u);
                wa[j] += hu * r0; wb[j] += hu * r1; wc[j] += hu * r2; wd[j] += hu * r3;
            }
        }
        #pragma unroll
        for (int j = 0; j < 4; ++j) {
            const int e = idx[j];
            const int dst = eidx[N_EDGES + e];
            const float4 sh = *(const float4*)(esh + (size_t)e*4);
            const float4 yd = *(const float4*)(ydata + ((size_t)dst*64 + lane)*4);
            acc0 += wa[j] * yd.x * sh.x;
            acc1 += wd[j] * (yd.y*sh.y + yd.z*sh.z + yd.w*sh.w) * 0.5773502691896258f;
            const float esb = wb[j] * yd.x;
            av0 += esb * sh.y; av1 += esb * sh.z; av2 += esb * sh.w;
            const float c0 = wc[j] * sh.x;
            bv0 += c0 * yd.y; bv1 += c0 * yd.z; bv2 += c0 * yd.w;
        }
    }
    float* nrow = ncat + ((size_t)n*64 + lane)*8;
    const float4 o0 = { acc0, av0, av1, av2 };
    const float4 o1 = { acc1, bv0, bv1, bv2 };
    *(float4*)(nrow)     = o0;
    *(float4*)(nrow + 4) = o1;
}

// ---------------- K3: node post-GEMM + RMS via MFMA ----------------
__global__ __launch_bounds__(256) void k3_mfma(
    const float* __restrict__ ncat, const int* __restrict__ start,
    const short* __restrict__ wp2, const float* __restrict__ scpack,
    const float* __restrict__ gs, const float* __restrict__ gv,
    float* __restrict__ out)
{
    const int lane = threadIdx.x & 63;
    const int tile = blockIdx.x * 4 + (threadIdx.x >> 6);
    if (tile >= N_TILES) return;
    const int l15 = lane & 15, lhi = lane >> 4;
    const int n = tile*16 + l15;
    const f32x4 zz = {0.f, 0.f, 0.f, 0.f};
    f32x4 acc[4][4];
    #pragma unroll
    for (int c = 0; c < 4; ++c)
        #pragma unroll
        for (int vt = 0; vt < 4; ++vt) acc[c][vt] = zz;

    #pragma unroll
    for (int kk = 0; kk < 4; ++kk) {
        const int u0 = (kk & 1)*32 + lhi*8;
        const int c = (kk >> 1)*4;
        float4 ld[8];
        #pragma unroll
        for (int j = 0; j < 8; ++j)
            ld[j] = *(const float4*)(ncat + ((size_t)n*64 + u0 + j)*8 + c);
        union { u32x4 u; bf16x8 v; } bs, b0, b1, b2;
        #pragma unroll
        for (int q = 0; q < 4; ++q) {
            bs.u[q] = cvt_pk(ld[2*q].x, ld[2*q+1].x);
            b0.u[q] = cvt_pk(ld[2*q].y, ld[2*q+1].y);
            b1.u[q] = cvt_pk(ld[2*q].z, ld[2*q+1].z);
            b2.u[q] = cvt_pk(ld[2*q].w, ld[2*q+1].w);
        }
        #pragma unroll
        for (int vt = 0; vt < 4; ++vt) {
            const int fo = ((vt*4 + kk)*64 + lane)*8;
            const bf16x8 a_s = *(const bf16x8*)&wp2[fo];
            const bf16x8 a_v = *(const bf16x8*)&wp2[8192 + fo];
            acc[0][vt] = MFMA16(a_s, bs.v, acc[0][vt]);
            acc[1][vt] = MFMA16(a_v, b0.v, acc[1][vt]);
            acc[2][vt] = MFMA16(a_v, b1.v, acc[2][vt]);
            acc[3][vt] = MFMA16(a_v, b2.v, acc[3][vt]);
        }
    }
    const float degf = (float)(start[n+1] - start[n]);
    const float coef = rsqrtf(fmaxf(degf, 1.0f)) * 0.08838834764831845f;
    float os[4][4], o0[4][4], o1[4][4], o2[4][4];
    float ssq = 0.f, vsq = 0.f;
    #pragma unroll
    for (int vt = 0; vt < 4; ++vt)
        #pragma unroll
        for (int r = 0; r < 4; ++r) {
            const int v = vt*16 + lhi*4 + r;
            const float4 sc = *(const float4*)(scpack + ((size_t)n*64 + v)*4);
            os[vt][r] = acc[0][vt][r]*coef + sc.x;
            o0[vt][r] = acc[1][vt][r]*coef + sc.y;
            o1[vt][r] = acc[2][vt][r]*coef + sc.z;
            o2[vt][r] = acc[3][vt][r]*coef + sc.w;
            ssq += os[vt][r]*os[vt][r];
            vsq += o0[vt][r]*o0[vt][r] + o1[vt][r]*o1[vt][r] + o2[vt][r]*o2[vt][r];
        }
    ssq += __shfl_xor(ssq, 16); ssq += __shfl_xor(ssq, 32);
    vsq += __shfl_xor(vsq, 16); vsq += __shfl_xor(vsq, 32);
    const float rs = rsqrtf(ssq * (1.0f/64.0f) + 1e-5f);
    const float rv = rsqrtf(vsq * (1.0f/192.0f) + 1e-5f);
    float* orow = out + (size_t)n * 256;
    #pragma unroll
    for (int vt = 0; vt < 4; ++vt) {
        const int vb = vt*16 + lhi*4;
        const float4 g4  = *(const float4*)(gs + vb);
        const float4 gv4 = *(const float4*)(gv + vb);
        const float4 so = { os[vt][0]*rs*g4.x, os[vt][1]*rs*g4.y,
                            os[vt][2]*rs*g4.z, os[vt][3]*rs*g4.w };
        *(float4*)(orow + vb) = so;
        const float m0 = rv*gv4.x, m1 = rv*gv4.y, m2 = rv*gv4.z, m3 = rv*gv4.w;
        const float4 w0 = { o0[vt][0]*m0, o1[vt][0]*m0, o2[vt][0]*m0, o0[vt][1]*m1 };
        const float4 w1 = { o1[vt][1]*m1, o2[vt][1]*m1, o0[vt][2]*m2, o1[vt][2]*m2 };
        const float4 w2 = { o2[vt][2]*m2, o0[vt][3]*m3, o1[vt][3]*m3, o2[vt][3]*m3 };
        float* vbase = orow + 64 + vb*3;
        *(float4*)(vbase)     = w0;
        *(float4*)(vbase + 4) = w1;
        *(float4*)(vbase + 8) = w2;
    }
}

extern "C" void kernel_launch(void* const* d_in, const int* in_sizes, int n_in,
                              void* d_out, int out_size, void* d_ws, size_t ws_size,
                              hipStream_t stream) {
    const float* nh   = (const float*)d_in[0];
    const float* ea   = (const float*)d_in[1];
    const float* esh  = (const float*)d_in[2];
    const float* w1s  = (const float*)d_in[3];
    const float* w1v  = (const float*)d_in[4];
    const float* wscs = (const float*)d_in[5];
    const float* wscv = (const float*)d_in[6];
    const float* w2s  = (const float*)d_in[7];
    const float* w2v  = (const float*)d_in[8];
    const float* fcw1 = (const float*)d_in[9];
    const float* fcw2 = (const float*)d_in[10];
    const float* fcw3 = (const float*)d_in[11];
    const float* gs   = (const float*)d_in[12];
    const float* gv   = (const float*)d_in[13];
    const int*   eidx = (const int*)d_in[14];
    float* out = (float*)d_out;

    float* wsf = (float*)d_ws;
    size_t off = 0;
    float* ydata  = wsf + off; off += (size_t)N_NODES * 256;
    float* scpack = wsf + off; off += (size_t)N_NODES * 256;
    float* ncat   = wsf + off; off += (size_t)N_NODES * 512;
    float* esh_perm = wsf + off; off += (size_t)N_EDGES * 4;
    int* ibase    = (int*)(wsf + off);
    int* cnt      = ibase;                        // cursor after scan
    int* start    = ibase + N_NODES;              // N_NODES+1
    int* perm     = ibase + 2*N_NODES + 1;        // N_EDGES
    int* dst_perm = perm + N_EDGES;               // N_EDGES
    short* w1A = (short*)(dst_perm + N_EDGES);
    short* w2A = w1A + 2048;
    short* w3A = w2A + 4096;
    short* wp1 = w3A + 16384;
    short* wp2 = wp1 + 16384;
    size_t used = (size_t)((char*)(wp2 + 16384) - (char*)d_ws);
    size_t wq_off = (used + 15) & ~(size_t)15;
    short* wq = (short*)((char*)d_ws + wq_off);
    const size_t need = wq_off + (size_t)N_EDGES * 256 * 2;

    hipMemsetAsync(cnt, 0, N_NODES * sizeof(int), stream);

    s_hist<<<(N_EDGES + 255)/256, 256, 0, stream>>>(eidx, cnt);
    s_scan<<<1, 1024, 0, stream>>>(cnt, start);
    s_scatter<<<(N_EDGES + 255)/256, 256, 0, stream>>>(
        eidx, esh, cnt, perm, dst_perm, esh_perm);

    k_pack<<<32, 256, 0, stream>>>(fcw1, fcw2, fcw3, w1s, wscs, w1v, wscv,
                                   w2s, w2v, w1A, w2A, w3A, wp1, wp2);

    k1_mfma<<<(N_TILES + 3)/4, 256, 0, stream>>>(nh, wp1, ydata, scpack);

    if (ws_size >= need) {
        k_mlp<<<N_EDGES/256, 256, 0, stream>>>(ea, perm, w1A, w2A, w3A, wq);
        k2_gather<<<(N_NODES + 3)/4, 256, 0, stream>>>(
            start, dst_perm, esh_perm, wq, ydata, ncat);
    } else {
        k2_seg<<<(N_NODES + 3)/4, 256, 0, stream>>>(
            ea, esh, eidx, perm, start, fcw1, fcw2, fcw3, ydata, ncat);
    }

    k3_mfma<<<(N_TILES + 3)/4, 256, 0, stream>>>(
        ncat, start, wp2, scpack, gs, gv, out);
}

// Round 6
// 227.602 us; speedup vs baseline: 7.2843x; 1.2135x over previous
//
#include <hip/hip_runtime.h>
#include <math.h>

#define N_NODES 20000
#define N_EDGES 320000
#define N_TILES 1250   // N_NODES / 16

typedef __attribute__((ext_vector_type(8))) short bf16x8;
typedef __attribute__((ext_vector_type(4))) float f32x4;
typedef __attribute__((ext_vector_type(2))) unsigned u32x2;
typedef __attribute__((ext_vector_type(4))) unsigned u32x4;

__device__ __forceinline__ float silu_f(float x) {
    return x / (1.0f + __expf(-x));
}
__device__ __forceinline__ short f2bf(float x) {
    union { float f; unsigned u; } v; v.f = x;
    unsigned r = (v.u + 0x7FFFu + ((v.u >> 16) & 1u)) >> 16;
    return (short)r;
}
__device__ __forceinline__ float blo(unsigned u) { return __uint_as_float(u << 16); }
__device__ __forceinline__ float bhi(unsigned u) { return __uint_as_float(u & 0xFFFF0000u); }
__device__ __forceinline__ unsigned cvt_pk(float lo, float hi) {
    unsigned r;
    asm("v_cvt_pk_bf16_f32 %0, %1, %2" : "=v"(r) : "v"(lo), "v"(hi));
    return r;
}
__device__ __forceinline__ float rlane(float v, int l) {
    return __uint_as_float(__builtin_amdgcn_readlane(__float_as_uint(v), l));
}
#define MFMA16(a, b, c) __builtin_amdgcn_mfma_f32_16x16x32_bf16((a), (b), (c), 0, 0, 0)

// ---------------- sort pass ----------------
__global__ __launch_bounds__(256) void s_hist(const int* __restrict__ eidx,
                                              int* __restrict__ cnt) {
    const int e = blockIdx.x * 256 + threadIdx.x;
    if (e < N_EDGES) atomicAdd(&cnt[eidx[e]], 1);
}

__global__ __launch_bounds__(1024) void s_scan(int* __restrict__ cnt,
                                               int* __restrict__ start) {
    const int tid = threadIdx.x;
    const int base = tid * 20;
    int vals[20];
    int sum = 0;
    #pragma unroll
    for (int j = 0; j < 20; ++j) {
        const int i = base + j;
        const int v = (i < N_NODES) ? cnt[i] : 0;
        vals[j] = sum;
        sum += v;
    }
    const int lane = tid & 63, wv = tid >> 6;
    int x = sum;
    #pragma unroll
    for (int off = 1; off < 64; off <<= 1) {
        const int t = __shfl_up(x, off);
        if (lane >= off) x += t;
    }
    __shared__ int wtot[16];
    if (lane == 63) wtot[wv] = x;
    __syncthreads();
    int wpref = 0;
    for (int k = 0; k < wv; ++k) wpref += wtot[k];
    const int excl = wpref + x - sum;
    #pragma unroll
    for (int j = 0; j < 20; ++j) {
        const int i = base + j;
        if (i < N_NODES) {
            const int s = excl + vals[j];
            start[i] = s;
            cnt[i] = s;   // cnt doubles as cursor
        }
    }
    if (tid == 1023) start[N_NODES] = wpref + x;
}

__global__ __launch_bounds__(256) void s_scatter(const int* __restrict__ eidx,
                                                 const float* __restrict__ esh,
                                                 int* __restrict__ cursor,
                                                 int* __restrict__ perm,
                                                 int* __restrict__ dst_perm,
                                                 float* __restrict__ esh_perm) {
    const int e = blockIdx.x * 256 + threadIdx.x;
    if (e >= N_EDGES) return;
    const int src = eidx[e];
    const int pos = atomicAdd(&cursor[src], 1);
    perm[pos] = e;
    dst_perm[pos] = eidx[N_EDGES + e];
    *(float4*)(esh_perm + (size_t)pos * 4) = *(const float4*)(esh + (size_t)e * 4);
}

// ---------------- weight prepack ----------------
__global__ __launch_bounds__(256) void k_pack(
    const float* __restrict__ fcw1, const float* __restrict__ fcw2,
    const float* __restrict__ fcw3,
    const float* __restrict__ w1s, const float* __restrict__ wscs,
    const float* __restrict__ w1v, const float* __restrict__ wscv,
    const float* __restrict__ w2s, const float* __restrict__ w2v,
    short* __restrict__ w1A, short* __restrict__ w2A, short* __restrict__ w3A,
    short* __restrict__ wp1, short* __restrict__ wp2)
{
    const int tid = blockIdx.x * 256 + threadIdx.x;
    const int nthr = gridDim.x * 256;
    for (int i = tid; i < 4*64*8; i += nthr) {           // fc_w1^T, K padded
        const int j = i & 7, lane = (i >> 3) & 63, t = i >> 9;
        const int k = (lane >> 4) * 8 + j, row = t*16 + (lane & 15);
        w1A[i] = (k < 8) ? f2bf(fcw1[k*64 + row]) : (short)0;
    }
    for (int i = tid; i < 8*64*8; i += nthr) {           // fc_w2^T
        const int j = i & 7, lane = (i >> 3) & 63, kk = (i >> 9) & 1, t = i >> 10;
        const int k = kk*32 + (lane >> 4)*8 + j, row = t*16 + (lane & 15);
        w2A[i] = f2bf(fcw2[k*64 + row]);
    }
    for (int i = tid; i < 32*64*8; i += nthr) {          // fc_w3^T (wD * 1/sqrt3 folded)
        const int j = i & 7, lane = (i >> 3) & 63, kk = (i >> 9) & 1, T = i >> 10;
        const int k = kk*32 + (lane >> 4)*8 + j, c = T*16 + (lane & 15);
        const float s = (c >= 192) ? 0.5773502691896258f : 1.0f;
        w3A[i] = f2bf(fcw3[(size_t)k*256 + c] * s);
    }
    for (int i = tid; i < 4096; i += nthr) {             // k1 weights (64x64)
        const int j = i & 7, lane = (i >> 3) & 63, kk = (i >> 9) & 1, vt = i >> 10;
        const int row = vt*16 + (lane & 15), k = kk*32 + (lane >> 4)*8 + j;
        wp1[i]         = f2bf(w1s [k*64 + row]);
        wp1[4096 + i]  = f2bf(wscs[k*64 + row]);
        wp1[8192 + i]  = f2bf(w1v [k*64 + row]);
        wp1[12288 + i] = f2bf(wscv[k*64 + row]);
    }
    for (int i = tid; i < 8192; i += nthr) {             // k3 weights, k = u*2+bank remap
        const int j = i & 7, lane = (i >> 3) & 63, kk = (i >> 9) & 3, vt = i >> 11;
        const int row = vt*16 + (lane & 15), k = kk*32 + (lane >> 4)*8 + j;
        const int r = (k & 1)*64 + (k >> 1);
        wp2[i]        = f2bf(w2s[r*64 + row]);
        wp2[8192 + i] = f2bf(w2v[r*64 + row]);
    }
}

// ---------------- K1: node pre-GEMMs via MFMA, bf16-packed outputs ----------------
__global__ __launch_bounds__(256) void k1_mfma(
    const float* __restrict__ nh, const short* __restrict__ wp1,
    short* __restrict__ ydata, short* __restrict__ scpack)
{
    const int lane = threadIdx.x & 63;
    const int tile = blockIdx.x * 4 + (threadIdx.x >> 6);
    if (tile >= N_TILES) return;
    const int l15 = lane & 15, lhi = lane >> 4;
    const int n = tile*16 + l15;
    const float* row = nh + (size_t)n * 256;
    const f32x4 zz = {0.f, 0.f, 0.f, 0.f};
    f32x4 acc[8][4];
    #pragma unroll
    for (int c = 0; c < 8; ++c)
        #pragma unroll
        for (int vt = 0; vt < 4; ++vt) acc[c][vt] = zz;

    #pragma unroll
    for (int kk = 0; kk < 2; ++kk) {
        const int k0 = kk*32 + lhi*8;
        const float4 s0 = *(const float4*)(row + k0);
        const float4 s1 = *(const float4*)(row + k0 + 4);
        float4 vv[6];
        #pragma unroll
        for (int q = 0; q < 6; ++q) vv[q] = *(const float4*)(row + 64 + 3*k0 + q*4);
        const float* vf = (const float*)vv;
        union { u32x4 u; bf16x8 v; } bs, b0, b1, b2;
        bs.u[0] = cvt_pk(s0.x, s0.y); bs.u[1] = cvt_pk(s0.z, s0.w);
        bs.u[2] = cvt_pk(s1.x, s1.y); bs.u[3] = cvt_pk(s1.z, s1.w);
        #pragma unroll
        for (int q = 0; q < 4; ++q) {
            b0.u[q] = cvt_pk(vf[6*q + 0], vf[6*q + 3]);
            b1.u[q] = cvt_pk(vf[6*q + 1], vf[6*q + 4]);
            b2.u[q] = cvt_pk(vf[6*q + 2], vf[6*q + 5]);
        }
        #pragma unroll
        for (int vt = 0; vt < 4; ++vt) {
            const int fo = ((vt*2 + kk)*64 + lane)*8;
            const bf16x8 a_ys = *(const bf16x8*)&wp1[fo];
            const bf16x8 a_ss = *(const bf16x8*)&wp1[4096 + fo];
            const bf16x8 a_yv = *(const bf16x8*)&wp1[8192 + fo];
            const bf16x8 a_sv = *(const bf16x8*)&wp1[12288 + fo];
            acc[0][vt] = MFMA16(a_ys, bs.v, acc[0][vt]);
            acc[1][vt] = MFMA16(a_ss, bs.v, acc[1][vt]);
            acc[2][vt] = MFMA16(a_yv, b0.v, acc[2][vt]);
            acc[3][vt] = MFMA16(a_yv, b1.v, acc[3][vt]);
            acc[4][vt] = MFMA16(a_yv, b2.v, acc[4][vt]);
            acc[5][vt] = MFMA16(a_sv, b0.v, acc[5][vt]);
            acc[6][vt] = MFMA16(a_sv, b1.v, acc[6][vt]);
            acc[7][vt] = MFMA16(a_sv, b2.v, acc[7][vt]);
        }
    }
    #pragma unroll
    for (int vt = 0; vt < 4; ++vt)
        #pragma unroll
        for (int r = 0; r < 4; ++r) {
            const int v = vt*16 + lhi*4 + r;
            u32x2 yo, so;
            yo[0] = cvt_pk(acc[0][vt][r]*0.125f, acc[2][vt][r]*0.125f);
            yo[1] = cvt_pk(acc[3][vt][r]*0.125f, acc[4][vt][r]*0.125f);
            so[0] = cvt_pk(acc[1][vt][r]*0.125f, acc[5][vt][r]*0.125f);
            so[1] = cvt_pk(acc[6][vt][r]*0.125f, acc[7][vt][r]*0.125f);
            *(u32x2*)&ydata [((size_t)n*64 + v)*4] = yo;
            *(u32x2*)&scpack[((size_t)n*64 + v)*4] = so;
        }
}

// ---------------- K_mlp: MFMA edge MLP; wq layout [slot][v][4ch] ----------------
__global__ __launch_bounds__(256) void k_mlp(
    const float* __restrict__ ea, const int* __restrict__ perm,
    const short* __restrict__ w1A, const short* __restrict__ w2A,
    const short* __restrict__ w3A, short* __restrict__ wq)
{
    __shared__ short hb1[4][1024];
    __shared__ short hb2[4][1024];
    const int lane = threadIdx.x & 63, w = threadIdx.x >> 6;
    const int l15 = lane & 15, lhi = lane >> 4;
    const int wbase = (blockIdx.x * 4 + w) * 64;
    short* h1b = hb1[w];
    short* h2b = hb2[w];
    const int swz = (l15 & 7) << 4;
    const f32x4 zz = {0.f, 0.f, 0.f, 0.f};

    bf16x8 a1[4], a2[4][2];
    #pragma unroll
    for (int t = 0; t < 4; ++t)
        a1[t] = *(const bf16x8*)&w1A[(t*64 + lane)*8];
    #pragma unroll
    for (int t = 0; t < 4; ++t)
        #pragma unroll
        for (int kk = 0; kk < 2; ++kk)
            a2[t][kk] = *(const bf16x8*)&w2A[((t*2 + kk)*64 + lane)*8];

    bf16x8 bh2[4][2];
    for (int sb = 0; sb < 4; ++sb) {
        bf16x8 bea = {0,0,0,0,0,0,0,0};
        if (lhi == 0) {
            const int e = perm[wbase + sb*16 + l15];
            const float4 p0 = *(const float4*)(ea + (size_t)e*8);
            const float4 p1 = *(const float4*)(ea + (size_t)e*8 + 4);
            union { u32x4 u; bf16x8 v; } tu;
            tu.u[0] = cvt_pk(p0.x, p0.y);
            tu.u[1] = cvt_pk(p0.z, p0.w);
            tu.u[2] = cvt_pk(p1.x, p1.y);
            tu.u[3] = cvt_pk(p1.z, p1.w);
            bea = tu.v;
        }
        f32x4 d1[4];
        #pragma unroll
        for (int t = 0; t < 4; ++t)
            d1[t] = MFMA16(a1[t], bea, zz);
        #pragma unroll
        for (int t = 0; t < 4; ++t) {
            const float s0 = silu_f(d1[t][0] * 0.35355339059327373f);
            const float s1 = silu_f(d1[t][1] * 0.35355339059327373f);
            const float s2 = silu_f(d1[t][2] * 0.35355339059327373f);
            const float s3 = silu_f(d1[t][3] * 0.35355339059327373f);
            u32x2 pk; pk[0] = cvt_pk(s0, s1); pk[1] = cvt_pk(s2, s3);
            const int byt = (l15*128 + t*32 + lhi*8) ^ swz;
            *(u32x2*)((char*)h1b + byt) = pk;
        }
        bf16x8 bh1[2];
        #pragma unroll
        for (int kk = 0; kk < 2; ++kk)
            bh1[kk] = *(const bf16x8*)((const char*)h1b + ((l15*128 + kk*64 + lhi*16) ^ swz));
        f32x4 d2[4];
        #pragma unroll
        for (int t = 0; t < 4; ++t) {
            d2[t] = MFMA16(a2[t][0], bh1[0], zz);
            d2[t] = MFMA16(a2[t][1], bh1[1], d2[t]);
        }
        #pragma unroll
        for (int t = 0; t < 4; ++t) {
            const float s0 = silu_f(d2[t][0] * 0.125f) * 0.125f;
            const float s1 = silu_f(d2[t][1] * 0.125f) * 0.125f;
            const float s2 = silu_f(d2[t][2] * 0.125f) * 0.125f;
            const float s3 = silu_f(d2[t][3] * 0.125f) * 0.125f;
            u32x2 pk; pk[0] = cvt_pk(s0, s1); pk[1] = cvt_pk(s2, s3);
            const int byt = (l15*128 + t*32 + lhi*8) ^ swz;
            *(u32x2*)((char*)h2b + byt) = pk;
        }
        #pragma unroll
        for (int kk = 0; kk < 2; ++kk)
            bh2[sb][kk] = *(const bf16x8*)((const char*)h2b + ((l15*128 + kk*64 + lhi*16) ^ swz));
    }

    // L3 grouped by v-band c: T = q*4 + c -> ch = q*64 + (c*16 + lhi*4 + r)
    #pragma unroll
    for (int c = 0; c < 4; ++c) {
        f32x4 dq[4][4];  // [q][sb]
        #pragma unroll
        for (int q = 0; q < 4; ++q) {
            const int T = q*4 + c;
            const bf16x8 a30 = *(const bf16x8*)&w3A[((T*2 + 0)*64 + lane)*8];
            const bf16x8 a31 = *(const bf16x8*)&w3A[((T*2 + 1)*64 + lane)*8];
            #pragma unroll
            for (int sb = 0; sb < 4; ++sb) {
                f32x4 d = MFMA16(a30, bh2[sb][0], zz);
                dq[q][sb] = MFMA16(a31, bh2[sb][1], d);
            }
        }
        #pragma unroll
        for (int sb = 0; sb < 4; ++sb) {
            const int slot = wbase + sb*16 + l15;
            #pragma unroll
            for (int r = 0; r < 4; ++r) {
                const int v = c*16 + lhi*4 + r;
                u32x2 pk;
                pk[0] = cvt_pk(dq[0][sb][r], dq[1][sb][r]);
                pk[1] = cvt_pk(dq[2][sb][r], dq[3][sb][r]);
                *(u32x2*)&wq[((size_t)slot*64 + v)*4] = pk;
            }
        }
    }
}

// ---------------- K2: per-node gather + register segment-sum ----------------
__global__ __launch_bounds__(256) void k2_gather(
    const int* __restrict__ start, const int* __restrict__ dst_perm,
    const float* __restrict__ esh_perm, const short* __restrict__ wq,
    const short* __restrict__ ydata, unsigned* __restrict__ ncat32)
{
    const int lane = threadIdx.x & 63;
    const int n = blockIdx.x * 4 + (threadIdx.x >> 6);
    if (n >= N_NODES) return;
    const int s0 = start[n], s1 = start[n + 1];
    float acc0=0.f, acc1=0.f, av0=0.f, av1=0.f, av2=0.f, bv0=0.f, bv1=0.f, bv2=0.f;
    for (int p = s0; p < s1; p += 8) {
        const int m = s1 - p;
        u32x2 wv[8], yd[8];
        float4 sh[8];
        #pragma unroll
        for (int j = 0; j < 8; ++j) {
            const int pp = (j < m) ? p + j : s0;
            wv[j] = *(const u32x2*)&wq[((size_t)pp*64 + lane)*4];
            sh[j] = *(const float4*)(esh_perm + (size_t)pp*4);
            const int dst = dst_perm[pp];
            yd[j] = *(const u32x2*)&ydata[((size_t)dst*64 + lane)*4];
        }
        #pragma unroll
        for (int j = 0; j < 8; ++j) {
            const float g = (j < m) ? 1.f : 0.f;
            const float wa = blo(wv[j][0])*g, wb = bhi(wv[j][0])*g;
            const float wc = blo(wv[j][1])*g, wd = bhi(wv[j][1])*g;
            const float es  = blo(yd[j][0]), ev0 = bhi(yd[j][0]);
            const float ev1 = blo(yd[j][1]), ev2 = bhi(yd[j][1]);
            acc0 += wa * es * sh[j].x;
            acc1 += wd * (ev0*sh[j].y + ev1*sh[j].z + ev2*sh[j].w);  // 1/sqrt3 folded
            const float esb = wb * es;
            av0 += esb * sh[j].y; av1 += esb * sh[j].z; av2 += esb * sh[j].w;
            const float c0 = wc * sh[j].x;
            bv0 += c0 * ev0; bv1 += c0 * ev1; bv2 += c0 * ev2;
        }
    }
    unsigned* nrow = ncat32 + (size_t)n * 256;
    nrow[lane]        = cvt_pk(acc0, acc1);
    nrow[64  + lane]  = cvt_pk(av0, bv0);
    nrow[128 + lane]  = cvt_pk(av1, bv1);
    nrow[192 + lane]  = cvt_pk(av2, bv2);
}

// ---------------- fallback K2 (no-wq path) ----------------
__global__ __launch_bounds__(256) void k2_seg(
    const float* __restrict__ ea, const float* __restrict__ esh_perm,
    const int* __restrict__ perm, const int* __restrict__ dst_perm,
    const int* __restrict__ start,
    const float* __restrict__ fcw1, const float* __restrict__ fcw2,
    const float* __restrict__ fcw3,
    const short* __restrict__ ydata, unsigned* __restrict__ ncat32)
{
    __shared__ float lw1[8*64];
    __shared__ float lw2[64*64];
    for (int i = threadIdx.x; i < 8*64; i += 256)  lw1[i] = fcw1[i];
    for (int i = threadIdx.x; i < 64*64; i += 256) lw2[i] = fcw2[i];
    __syncthreads();
    const int lane = threadIdx.x & 63;
    const int n = blockIdx.x * 4 + (threadIdx.x >> 6);
    if (n >= N_NODES) return;
    const int s0 = start[n], s1 = start[n + 1];
    float acc0=0.f, acc1=0.f, av0=0.f, av1=0.f, av2=0.f, bv0=0.f, bv1=0.f, bv2=0.f;
    for (int p = s0; p < s1; p += 4) {
        int idx[4];
        float h1[4];
        #pragma unroll
        for (int j = 0; j < 4; ++j) {
            const bool ok = (p + j < s1);
            idx[j] = ok ? p + j : p;
            const float* eap = ea + (size_t)perm[idx[j]] * 8;
            float a = 0.f;
            #pragma unroll
            for (int u = 0; u < 8; ++u) a += eap[u] * lw1[u*64 + lane];
            a = ok ? a * 0.35355339059327373f : 0.f;
            h1[j] = silu_f(a);
        }
        float h2[4] = {0.f, 0.f, 0.f, 0.f};
        #pragma unroll 8
        for (int u = 0; u < 64; ++u) {
            const float wv = lw2[u*64 + lane];
            h2[0] += rlane(h1[0], u) * wv;
            h2[1] += rlane(h1[1], u) * wv;
            h2[2] += rlane(h1[2], u) * wv;
            h2[3] += rlane(h1[3], u) * wv;
        }
        #pragma unroll
        for (int j = 0; j < 4; ++j) h2[j] = silu_f(h2[j] * 0.125f) * 0.125f;
        float wa[4] = {0,0,0,0}, wb[4] = {0,0,0,0}, wc[4] = {0,0,0,0}, wd[4] = {0,0,0,0};
        #pragma unroll 4
        for (int u = 0; u < 64; ++u) {
            const float* r = fcw3 + u * 256;
            const float r0 = r[lane], r1 = r[64 + lane], r2 = r[128 + lane], r3 = r[192 + lane];
            #pragma unroll
            for (int j = 0; j < 4; ++j) {
                const float hu = rlane(h2[j], u);
                wa[j] += hu * r0; wb[j] += hu * r1; wc[j] += hu * r2; wd[j] += hu * r3;
            }
        }
        #pragma unroll
        for (int j = 0; j < 4; ++j) {
            const int pp = idx[j];
            const float4 sh = *(const float4*)(esh_perm + (size_t)pp*4);
            const int dst = dst_perm[pp];
            const u32x2 yd = *(const u32x2*)&ydata[((size_t)dst*64 + lane)*4];
            const float es  = blo(yd[0]), ev0 = bhi(yd[0]);
            const float ev1 = blo(yd[1]), ev2 = bhi(yd[1]);
            acc0 += wa[j] * es * sh.x;
            acc1 += wd[j] * (ev0*sh.y + ev1*sh.z + ev2*sh.w) * 0.5773502691896258f;
            const float esb = wb[j] * es;
            av0 += esb * sh.y; av1 += esb * sh.z; av2 += esb * sh.w;
            const float c0 = wc[j] * sh.x;
            bv0 += c0 * ev0; bv1 += c0 * ev1; bv2 += c0 * ev2;
        }
    }
    unsigned* nrow = ncat32 + (size_t)n * 256;
    nrow[lane]        = cvt_pk(acc0, acc1);
    nrow[64  + lane]  = cvt_pk(av0, bv0);
    nrow[128 + lane]  = cvt_pk(av1, bv1);
    nrow[192 + lane]  = cvt_pk(av2, bv2);
}

// ---------------- K3: node post-GEMM + RMS via MFMA, fragment-direct ncat ----------------
__global__ __launch_bounds__(256) void k3_mfma(
    const unsigned* __restrict__ ncat32, const int* __restrict__ start,
    const short* __restrict__ wp2, const short* __restrict__ scpack,
    const float* __restrict__ gs, const float* __restrict__ gv,
    float* __restrict__ out)
{
    const int lane = threadIdx.x & 63;
    const int tile = blockIdx.x * 4 + (threadIdx.x >> 6);
    if (tile >= N_TILES) return;
    const int l15 = lane & 15, lhi = lane >> 4;
    const int n = tile*16 + l15;
    const f32x4 zz = {0.f, 0.f, 0.f, 0.f};
    f32x4 acc[4][4];
    #pragma unroll
    for (int c = 0; c < 4; ++c)
        #pragma unroll
        for (int vt = 0; vt < 4; ++vt) acc[c][vt] = zz;

    const size_t nb = (size_t)n * 256;
    #pragma unroll
    for (int kk = 0; kk < 4; ++kk) {
        const int uo = kk*16 + lhi*4;
        union { u32x4 u; bf16x8 v; } bs, b0, b1, b2;
        bs.u = *(const u32x4*)&ncat32[nb +        uo];
        b0.u = *(const u32x4*)&ncat32[nb +  64 + uo];
        b1.u = *(const u32x4*)&ncat32[nb + 128 + uo];
        b2.u = *(const u32x4*)&ncat32[nb + 192 + uo];
        #pragma unroll
        for (int vt = 0; vt < 4; ++vt) {
            const int fo = ((vt*4 + kk)*64 + lane)*8;
            const bf16x8 a_s = *(const bf16x8*)&wp2[fo];
            const bf16x8 a_v = *(const bf16x8*)&wp2[8192 + fo];
            acc[0][vt] = MFMA16(a_s, bs.v, acc[0][vt]);
            acc[1][vt] = MFMA16(a_v, b0.v, acc[1][vt]);
            acc[2][vt] = MFMA16(a_v, b1.v, acc[2][vt]);
            acc[3][vt] = MFMA16(a_v, b2.v, acc[3][vt]);
        }
    }
    const float degf = (float)(start[n+1] - start[n]);
    const float coef = rsqrtf(fmaxf(degf, 1.0f)) * 0.08838834764831845f;
    float os[4][4], o0[4][4], o1[4][4], o2[4][4];
    float ssq = 0.f, vsq = 0.f;
    #pragma unroll
    for (int vt = 0; vt < 4; ++vt)
        #pragma unroll
        for (int r = 0; r < 4; ++r) {
            const int v = vt*16 + lhi*4 + r;
            const u32x2 sc = *(const u32x2*)&scpack[((size_t)n*64 + v)*4];
            os[vt][r] = acc[0][vt][r]*coef + blo(sc[0]);
            o0[vt][r] = acc[1][vt][r]*coef + bhi(sc[0]);
            o1[vt][r] = acc[2][vt][r]*coef + blo(sc[1]);
            o2[vt][r] = acc[3][vt][r]*coef + bhi(sc[1]);
            ssq += os[vt][r]*os[vt][r];
            vsq += o0[vt][r]*o0[vt][r] + o1[vt][r]*o1[vt][r] + o2[vt][r]*o2[vt][r];
        }
    ssq += __shfl_xor(ssq, 16); ssq += __shfl_xor(ssq, 32);
    vsq += __shfl_xor(vsq, 16); vsq += __shfl_xor(vsq, 32);
    const float rs = rsqrtf(ssq * (1.0f/64.0f) + 1e-5f);
    const float rv = rsqrtf(vsq * (1.0f/192.0f) + 1e-5f);
    float* orow = out + (size_t)n * 256;
    #pragma unroll
    for (int vt = 0; vt < 4; ++vt) {
        const int vb = vt*16 + lhi*4;
        const float4 g4  = *(const float4*)(gs + vb);
        const float4 gv4 = *(const float4*)(gv + vb);
        const float4 so = { os[vt][0]*rs*g4.x, os[vt][1]*rs*g4.y,
                            os[vt][2]*rs*g4.z, os[vt][3]*rs*g4.w };
        *(float4*)(orow + vb) = so;
        const float m0 = rv*gv4.x, m1 = rv*gv4.y, m2 = rv*gv4.z, m3 = rv*gv4.w;
        const float4 w0 = { o0[vt][0]*m0, o1[vt][0]*m0, o2[vt][0]*m0, o0[vt][1]*m1 };
        const float4 w1 = { o1[vt][1]*m1, o2[vt][1]*m1, o0[vt][2]*m2, o1[vt][2]*m2 };
        const float4 w2 = { o2[vt][2]*m2, o0[vt][3]*m3, o1[vt][3]*m3, o2[vt][3]*m3 };
        float* vbase = orow + 64 + vb*3;
        *(float4*)(vbase)     = w0;
        *(float4*)(vbase + 4) = w1;
        *(float4*)(vbase + 8) = w2;
    }
}

extern "C" void kernel_launch(void* const* d_in, const int* in_sizes, int n_in,
                              void* d_out, int out_size, void* d_ws, size_t ws_size,
                              hipStream_t stream) {
    const float* nh   = (const float*)d_in[0];
    const float* ea   = (const float*)d_in[1];
    const float* esh  = (const float*)d_in[2];
    const float* w1s  = (const float*)d_in[3];
    const float* w1v  = (const float*)d_in[4];
    const float* wscs = (const float*)d_in[5];
    const float* wscv = (const float*)d_in[6];
    const float* w2s  = (const float*)d_in[7];
    const float* w2v  = (const float*)d_in[8];
    const float* fcw1 = (const float*)d_in[9];
    const float* fcw2 = (const float*)d_in[10];
    const float* fcw3 = (const float*)d_in[11];
    const float* gs   = (const float*)d_in[12];
    const float* gv   = (const float*)d_in[13];
    const int*   eidx = (const int*)d_in[14];
    float* out = (float*)d_out;

    char* wsb = (char*)d_ws;
    size_t off = 0;
    short* ydata  = (short*)(wsb + off); off += (size_t)N_NODES * 256 * 2;   // bf16 [n][64][4]
    short* scpack = (short*)(wsb + off); off += (size_t)N_NODES * 256 * 2;   // bf16 [n][64][4]
    unsigned* ncat32 = (unsigned*)(wsb + off); off += (size_t)N_NODES * 256 * 4; // u32 [n][4][64]
    float* esh_perm  = (float*)(wsb + off); off += (size_t)N_EDGES * 4 * 4;
    int* cnt      = (int*)(wsb + off); off += (size_t)N_NODES * 4;
    int* start    = (int*)(wsb + off); off += ((size_t)N_NODES + 1) * 4;
    int* perm     = (int*)(wsb + off); off += (size_t)N_EDGES * 4;
    int* dst_perm = (int*)(wsb + off); off += (size_t)N_EDGES * 4;
    short* w1A = (short*)(wsb + off); off += 2048 * 2;
    short* w2A = (short*)(wsb + off); off += 4096 * 2;
    short* w3A = (short*)(wsb + off); off += 16384 * 2;
    short* wp1 = (short*)(wsb + off); off += 16384 * 2;
    short* wp2 = (short*)(wsb + off); off += 16384 * 2;
    off = (off + 15) & ~(size_t)15;
    short* wq = (short*)(wsb + off);
    const size_t need = off + (size_t)N_EDGES * 256 * 2;

    hipMemsetAsync(cnt, 0, N_NODES * sizeof(int), stream);

    s_hist<<<(N_EDGES + 255)/256, 256, 0, stream>>>(eidx, cnt);
    s_scan<<<1, 1024, 0, stream>>>(cnt, start);
    s_scatter<<<(N_EDGES + 255)/256, 256, 0, stream>>>(
        eidx, esh, cnt, perm, dst_perm, esh_perm);

    k_pack<<<32, 256, 0, stream>>>(fcw1, fcw2, fcw3, w1s, wscs, w1v, wscv,
                                   w2s, w2v, w1A, w2A, w3A, wp1, wp2);

    k1_mfma<<<(N_TILES + 3)/4, 256, 0, stream>>>(nh, wp1, ydata, scpack);

    if (ws_size >= need) {
        k_mlp<<<N_EDGES/256, 256, 0, stream>>>(ea, perm, w1A, w2A, w3A, wq);
        k2_gather<<<(N_NODES + 3)/4, 256, 0, stream>>>(
            start, dst_perm, esh_perm, wq, ydata, ncat32);
    } else {
        k2_seg<<<(N_NODES + 3)/4, 256, 0, stream>>>(
            ea, esh_perm, perm, dst_perm, start, fcw1, fcw2, fcw3, ydata, ncat32);
    }

    k3_mfma<<<(N_TILES + 3)/4, 256, 0, stream>>>(
        ncat32, start, wp2, scpack, gs, gv, out);
}